// Round 1
// baseline (310.870 us; speedup 1.0000x reference)
//
#include <hip/hip_runtime.h>
#include <stdint.h>

#define NT 8192      // sequence length
#define DM 256       // d_model
#define DI 512       // d_inner
#define DS 16        // d_state
#define DR 16        // dt_rank
#define NCH 256      // scan chunks
#define LCH 32       // chunk length (NCH*LCH == NT)

typedef __bf16 bf16_t;
typedef bf16_t bf16x8 __attribute__((ext_vector_type(8)));
typedef float f32x4 __attribute__((ext_vector_type(4)));

// ---------- helpers ----------
__device__ __forceinline__ unsigned short f2b(float f) {
    union { float f; unsigned int i; } v; v.f = f;
    unsigned int r = v.i + 0x7fffu + ((v.i >> 16) & 1u);   // RNE
    return (unsigned short)(r >> 16);
}
__device__ __forceinline__ float b2f(unsigned short u) {
    union { unsigned int i; float f; } v; v.i = ((unsigned int)u) << 16; return v.f;
}
__device__ __forceinline__ bf16x8 ld_frag_lds(const unsigned short* p) {
    union { uint4 u; bf16x8 b; } v;
    v.u = *(const uint4*)p;
    return v.b;
}

// ---------- fp32 -> bf16 conversion for x + 6 weight matrices ----------
struct CvtArgs {
    const float* src[7];
    unsigned short* dst[7];
    int cnt[7];
    int total;
};
__global__ __launch_bounds__(256) void cvt_all(CvtArgs a) {
    int i = blockIdx.x * 256 + threadIdx.x;
    if (i >= a.total) return;
    #pragma unroll
    for (int s = 0; s < 7; s++) {
        if (i < a.cnt[s]) { a.dst[s][i] = f2b(a.src[s][i]); return; }
        i -= a.cnt[s];
    }
}

// ---------- bf16 MFMA GEMM:  C[M,N] = A[M,K] @ B[N,K]^T  (+epilogue) ----------
// FLAGS: 1=bias  2=relu  4=residual(+resid[m*N+n])  8=store f32  16=store bf16
#define SROW 80   // LDS row stride (64 + 16 pad), keeps 16B alignment
template<int FLAGS>
__global__ __launch_bounds__(256) void gemm_bt(
    const unsigned short* __restrict__ A, const unsigned short* __restrict__ B,
    int M, int N, int K,
    const float* __restrict__ bias, const float* __restrict__ resid,
    float* __restrict__ Cf, unsigned short* __restrict__ Cb)
{
    __shared__ unsigned short sA[64 * SROW];
    __shared__ unsigned short sB[64 * SROW];
    const int tid = threadIdx.x;
    const int m0 = blockIdx.x * 64;
    const int n0 = blockIdx.y * 64;
    const int wave = tid >> 6, lane = tid & 63;
    const int wm = (wave & 1) * 32, wn = (wave >> 1) * 32;
    const int qm = lane >> 4, rm = lane & 15;

    f32x4 acc[2][2];
    #pragma unroll
    for (int i = 0; i < 2; i++)
        #pragma unroll
        for (int j = 0; j < 2; j++)
            #pragma unroll
            for (int r = 0; r < 4; r++) acc[i][j][r] = 0.f;

    for (int k0 = 0; k0 < K; k0 += 64) {
        __syncthreads();
        #pragma unroll
        for (int i = 0; i < 2; i++) {
            int chunk = tid + i * 256;            // 512 chunks of 8 bf16
            int r = chunk >> 3, c8 = chunk & 7;
            *(uint4*)&sA[r * SROW + c8 * 8] =
                *(const uint4*)(A + (size_t)(m0 + r) * K + k0 + c8 * 8);
            int nr = n0 + r;
            uint4 bv = make_uint4(0u, 0u, 0u, 0u);
            if (nr < N) bv = *(const uint4*)(B + (size_t)nr * K + k0 + c8 * 8);
            *(uint4*)&sB[r * SROW + c8 * 8] = bv;
        }
        __syncthreads();
        #pragma unroll
        for (int ks = 0; ks < 64; ks += 32) {
            bf16x8 af[2], bfr[2];
            #pragma unroll
            for (int i = 0; i < 2; i++) {
                af[i]  = ld_frag_lds(&sA[(wm + i * 16 + rm) * SROW + ks + qm * 8]);
                bfr[i] = ld_frag_lds(&sB[(wn + i * 16 + rm) * SROW + ks + qm * 8]);
            }
            #pragma unroll
            for (int i = 0; i < 2; i++)
                #pragma unroll
                for (int j = 0; j < 2; j++)
                    acc[i][j] = __builtin_amdgcn_mfma_f32_16x16x32_bf16(
                        af[i], bfr[j], acc[i][j], 0, 0, 0);
        }
    }

    // epilogue: D[m][n]: n = lane&15, m = (lane>>4)*4 + reg   [m89-verified layout]
    #pragma unroll
    for (int i = 0; i < 2; i++) {
        int mrow = m0 + wm + i * 16 + qm * 4;
        #pragma unroll
        for (int j = 0; j < 2; j++) {
            int ncol = n0 + wn + j * 16 + rm;
            if (ncol < N) {
                #pragma unroll
                for (int r = 0; r < 4; r++) {
                    float v = acc[i][j][r];
                    int mm = mrow + r;
                    if constexpr (FLAGS & 1) v += bias[ncol];
                    if constexpr (FLAGS & 4) v += resid[(size_t)mm * N + ncol];
                    if constexpr (FLAGS & 2) v = v > 0.f ? v : 0.f;
                    if constexpr (FLAGS & 8) Cf[(size_t)mm * N + ncol] = v;
                    if constexpr (FLAGS & 16) Cb[(size_t)mm * N + ncol] = f2b(v);
                }
            }
        }
    }
}

// ---------- depthwise causal conv (k=4) + SiLU ----------
__global__ __launch_bounds__(256) void conv_silu(
    const float* __restrict__ xz, const float* __restrict__ cw,
    const float* __restrict__ cb, float* __restrict__ xc,
    unsigned short* __restrict__ xcb)
{
    int idx = blockIdx.x * 256 + threadIdx.x;   // t*DI + d
    int d = idx & (DI - 1), t = idx >> 9;
    float v = cb[d];
    #pragma unroll
    for (int k = 0; k < 4; k++) {
        int tt = t - 3 + k;
        if (tt >= 0) v += xz[(size_t)tt * 1024 + d] * cw[d * 4 + k];
    }
    float s = v / (1.f + __expf(-v));
    xc[idx] = s;
    xcb[idx] = f2b(s);
}

// ---------- dt = softplus(dbl[:, :16] @ W_dt^T + b_dt) ----------
__global__ __launch_bounds__(256) void dt_proj(
    const float* __restrict__ dbl, const float* __restrict__ Wdt,
    const float* __restrict__ bdt, float* __restrict__ dt)
{
    int idx = blockIdx.x * 256 + threadIdx.x;   // t*DI + d
    int d = idx & (DI - 1), t = idx >> 9;
    const float* row = dbl + (size_t)t * 48;
    const float* w = Wdt + d * DR;
    float acc = bdt[d];
    #pragma unroll
    for (int j = 0; j < DR; j++) acc += row[j] * w[j];
    dt[idx] = acc > 20.f ? acc : log1pf(__expf(acc));
}

// ---------- scan phase 1: per-chunk decay product + local end-state ----------
__global__ __launch_bounds__(256) void scan1(
    const float* __restrict__ dt, const float* __restrict__ xc,
    const float* __restrict__ dbl, const float* __restrict__ A_log,
    float* __restrict__ Ac, float* __restrict__ Bc)
{
    __shared__ float sB[LCH][DS];
    const int d = blockIdx.x * 256 + threadIdx.x;  // 0..511
    const int c = blockIdx.y;
    const int t0 = c * LCH;
    #pragma unroll
    for (int r = 0; r < 2; r++) {
        int e = threadIdx.x + r * 256;
        sB[e >> 4][e & 15] = dbl[(size_t)(t0 + (e >> 4)) * 48 + 16 + (e & 15)];
    }
    __syncthreads();
    float A[DS], h[DS];
    #pragma unroll
    for (int s = 0; s < DS; s++) { A[s] = -__expf(A_log[d * DS + s]); h[s] = 0.f; }
    float sumdt = 0.f;
    for (int t = t0; t < t0 + LCH; t++) {
        float dtv = dt[(size_t)t * DI + d];
        float xcv = xc[(size_t)t * DI + d];
        float dtx = dtv * xcv;
        sumdt += dtv;
        #pragma unroll
        for (int s = 0; s < DS; s++) {
            float a = __expf(dtv * A[s]);
            h[s] = a * h[s] + dtx * sB[t - t0][s];
        }
    }
    #pragma unroll
    for (int s = 0; s < DS; s++) {
        size_t off = ((size_t)c * DS + s) * DI + d;
        Ac[off] = __expf(sumdt * A[s]);   // == prod_t exp(dt_t*A)
        Bc[off] = h[s];
    }
}

// ---------- scan phase 2: inter-chunk scan (8192 channels x NCH steps) ----------
__global__ __launch_bounds__(256) void scan2(
    const float* __restrict__ Ac, const float* __restrict__ Bc,
    float* __restrict__ Hc)
{
    int p = blockIdx.x * 256 + threadIdx.x;   // s*DI + d
    float h = 0.f;
    for (int c = 0; c < NCH; c++) {
        size_t off = (size_t)c * (DS * DI) + p;
        Hc[off] = h;
        h = Ac[off] * h + Bc[off];
    }
}

// ---------- scan phase 3: replay with true init; fuse +Dp*xc, *silu(z) ----------
__global__ __launch_bounds__(256) void scan3(
    const float* __restrict__ dt, const float* __restrict__ xc,
    const float* __restrict__ xz, const float* __restrict__ dbl,
    const float* __restrict__ A_log, const float* __restrict__ Dp,
    const float* __restrict__ Hc, unsigned short* __restrict__ ygb)
{
    __shared__ float sB[LCH][DS];
    __shared__ float sC[LCH][DS];
    const int d = blockIdx.x * 256 + threadIdx.x;
    const int c = blockIdx.y;
    const int t0 = c * LCH;
    #pragma unroll
    for (int r = 0; r < 2; r++) {
        int e = threadIdx.x + r * 256;
        int tt = e >> 4, s = e & 15;
        sB[tt][s] = dbl[(size_t)(t0 + tt) * 48 + 16 + s];
        sC[tt][s] = dbl[(size_t)(t0 + tt) * 48 + 32 + s];
    }
    __syncthreads();
    float A[DS], h[DS];
    #pragma unroll
    for (int s = 0; s < DS; s++) {
        A[s] = -__expf(A_log[d * DS + s]);
        h[s] = Hc[(size_t)c * (DS * DI) + s * DI + d];
    }
    float dpv = Dp[d];
    for (int t = t0; t < t0 + LCH; t++) {
        float dtv = dt[(size_t)t * DI + d];
        float xcv = xc[(size_t)t * DI + d];
        float zv  = xz[(size_t)t * 1024 + DI + d];
        float dtx = dtv * xcv;
        float y = 0.f;
        #pragma unroll
        for (int s = 0; s < DS; s++) {
            float a = __expf(dtv * A[s]);
            h[s] = a * h[s] + dtx * sB[t - t0][s];
            y += h[s] * sC[t - t0][s];
        }
        float sz = zv / (1.f + __expf(-zv));
        ygb[(size_t)t * DI + d] = f2b((y + dpv * xcv) * sz);
    }
}

// ---------- LayerNorm over 256 cols (one wave per row); optional add X2 ----------
__global__ __launch_bounds__(256) void lnorm(
    const float* __restrict__ X, const float* __restrict__ X2,
    const float* __restrict__ g, const float* __restrict__ b,
    float* __restrict__ outf, unsigned short* __restrict__ outb)
{
    int wave = threadIdx.x >> 6, lane = threadIdx.x & 63;
    int row = blockIdx.x * 4 + wave;
    const float* x = X + (size_t)row * DM;
    float v[4];
    #pragma unroll
    for (int i = 0; i < 4; i++) {
        int col = lane + i * 64;
        v[i] = x[col];
        if (X2) v[i] += X2[(size_t)row * DM + col];
    }
    float s = v[0] + v[1] + v[2] + v[3];
    float s2 = v[0]*v[0] + v[1]*v[1] + v[2]*v[2] + v[3]*v[3];
    #pragma unroll
    for (int m = 1; m < 64; m <<= 1) {
        s  += __shfl_xor(s, m, 64);
        s2 += __shfl_xor(s2, m, 64);
    }
    float mean = s * (1.f / DM);
    float var = s2 * (1.f / DM) - mean * mean;
    float inv = rsqrtf(var + 1e-5f);
    #pragma unroll
    for (int i = 0; i < 4; i++) {
        int col = lane + i * 64;
        float o = (v[i] - mean) * inv * g[col] + b[col];
        if (outf) outf[(size_t)row * DM + col] = o;
        if (outb) outb[(size_t)row * DM + col] = f2b(o);
    }
}

// ---------- workspace layout (bytes) ----------
static constexpr size_t OFF_XZ    = 0;            // f32 [8192][1024]   33554432
static constexpr size_t OFF_XC    = 33554432;     // f32 [8192][512]    16777216
static constexpr size_t OFF_XCB   = 50331648;     // bf16 [8192][512]    8388608
static constexpr size_t OFF_DBL   = 58720256;     // f32 [8192][48]      1572864
static constexpr size_t OFF_DT    = 60293120;     // f32 [8192][512]    16777216
static constexpr size_t OFF_AC    = 77070336;     // f32 [256][16][512]  8388608
static constexpr size_t OFF_BC    = 85458944;     // f32                 8388608
static constexpr size_t OFF_HC    = 93847552;     // f32                 8388608
static constexpr size_t OFF_YGB   = 102236160;    // bf16 [8192][512]    8388608
static constexpr size_t OFF_XB    = 110624768;    // bf16 [8192][256]    4194304
static constexpr size_t OFF_WINB  = 114819072;    // bf16 [1024][256]     524288
static constexpr size_t OFF_WXB   = 115343360;    // bf16 [48][512]        49152
static constexpr size_t OFF_WOUTB = 115392512;    // bf16 [256][512]      262144
static constexpr size_t OFF_WLINB = 115654656;    // bf16 [256][256]      131072
static constexpr size_t OFF_WEXPB = 115785728;    // bf16 [512][256]      262144
static constexpr size_t OFF_WSQB  = 116047872;    // bf16 [256][512]      262144
// aliases (safe: xz/xc/dt dead after scan3)
static constexpr size_t OFF_H1B   = OFF_XZ;                // bf16 [8192][256]
static constexpr size_t OFF_H2    = OFF_XZ + 4194304;      // f32  [8192][256]
static constexpr size_t OFF_HLN   = OFF_XZ + 12582912;     // f32  [8192][256]
static constexpr size_t OFF_HLNB  = OFF_XZ + 20971520;     // bf16 [8192][256]
static constexpr size_t OFF_FF1B  = OFF_DT;                // bf16 [8192][512]
static constexpr size_t OFF_FF2   = OFF_DT + 8388608;      // f32  [8192][256]

extern "C" void kernel_launch(void* const* d_in, const int* in_sizes, int n_in,
                              void* d_out, int out_size, void* d_ws, size_t ws_size,
                              hipStream_t stream)
{
    const float* x      = (const float*)d_in[0];
    const float* W_in   = (const float*)d_in[2];
    const float* conv_w = (const float*)d_in[3];
    const float* conv_b = (const float*)d_in[4];
    const float* W_x    = (const float*)d_in[5];
    const float* W_dt   = (const float*)d_in[6];
    const float* b_dt   = (const float*)d_in[7];
    const float* A_log  = (const float*)d_in[8];
    const float* Dp     = (const float*)d_in[9];
    const float* W_out  = (const float*)d_in[10];
    const float* W_lin  = (const float*)d_in[11];
    const float* b_lin  = (const float*)d_in[12];
    const float* ln1_g  = (const float*)d_in[13];
    const float* ln1_b  = (const float*)d_in[14];
    const float* W_exp  = (const float*)d_in[15];
    const float* b_exp  = (const float*)d_in[16];
    const float* W_sq   = (const float*)d_in[17];
    const float* b_sq   = (const float*)d_in[18];
    const float* ln2_g  = (const float*)d_in[19];
    const float* ln2_b  = (const float*)d_in[20];

    char* ws = (char*)d_ws;
    float* xz   = (float*)(ws + OFF_XZ);
    float* xc   = (float*)(ws + OFF_XC);
    unsigned short* xcb = (unsigned short*)(ws + OFF_XCB);
    float* dbl  = (float*)(ws + OFF_DBL);
    float* dtf  = (float*)(ws + OFF_DT);
    float* Ac   = (float*)(ws + OFF_AC);
    float* Bc   = (float*)(ws + OFF_BC);
    float* Hc   = (float*)(ws + OFF_HC);
    unsigned short* ygb   = (unsigned short*)(ws + OFF_YGB);
    unsigned short* xb    = (unsigned short*)(ws + OFF_XB);
    unsigned short* winb  = (unsigned short*)(ws + OFF_WINB);
    unsigned short* wxb   = (unsigned short*)(ws + OFF_WXB);
    unsigned short* woutb = (unsigned short*)(ws + OFF_WOUTB);
    unsigned short* wlinb = (unsigned short*)(ws + OFF_WLINB);
    unsigned short* wexpb = (unsigned short*)(ws + OFF_WEXPB);
    unsigned short* wsqb  = (unsigned short*)(ws + OFF_WSQB);
    unsigned short* h1b   = (unsigned short*)(ws + OFF_H1B);
    float* h2   = (float*)(ws + OFF_H2);
    float* hln  = (float*)(ws + OFF_HLN);
    unsigned short* hlnb  = (unsigned short*)(ws + OFF_HLNB);
    unsigned short* ff1b  = (unsigned short*)(ws + OFF_FF1B);
    float* ff2  = (float*)(ws + OFF_FF2);
    float* outp = (float*)d_out;

    // 1. bf16 conversions (x + 6 weight matrices)
    CvtArgs ca;
    ca.src[0] = x;     ca.dst[0] = xb;    ca.cnt[0] = NT * DM;
    ca.src[1] = W_in;  ca.dst[1] = winb;  ca.cnt[1] = 1024 * DM;
    ca.src[2] = W_x;   ca.dst[2] = wxb;   ca.cnt[2] = 48 * DI;
    ca.src[3] = W_out; ca.dst[3] = woutb; ca.cnt[3] = DM * DI;
    ca.src[4] = W_lin; ca.dst[4] = wlinb; ca.cnt[4] = DM * DM;
    ca.src[5] = W_exp; ca.dst[5] = wexpb; ca.cnt[5] = DI * DM;
    ca.src[6] = W_sq;  ca.dst[6] = wsqb;  ca.cnt[6] = DM * DI;
    ca.total = ca.cnt[0]+ca.cnt[1]+ca.cnt[2]+ca.cnt[3]+ca.cnt[4]+ca.cnt[5]+ca.cnt[6];
    cvt_all<<<(ca.total + 255) / 256, 256, 0, stream>>>(ca);

    // 2. xz = x @ W_in^T        [8192,1024]
    gemm_bt<8><<<dim3(128, 16), 256, 0, stream>>>(xb, winb, NT, 1024, DM,
                                                  nullptr, nullptr, xz, nullptr);
    // 3. causal depthwise conv + silu
    conv_silu<<<NT * DI / 256, 256, 0, stream>>>(xz, conv_w, conv_b, xc, xcb);
    // 4. dbl = xc @ W_x^T       [8192,48]
    gemm_bt<8><<<dim3(128, 1), 256, 0, stream>>>(xcb, wxb, NT, 48, DI,
                                                 nullptr, nullptr, dbl, nullptr);
    // 5. dt = softplus(dbl[:,:16] @ W_dt^T + b_dt)
    dt_proj<<<NT * DI / 256, 256, 0, stream>>>(dbl, W_dt, b_dt, dtf);
    // 6-8. chunked selective scan
    scan1<<<dim3(2, NCH), 256, 0, stream>>>(dtf, xc, dbl, A_log, Ac, Bc);
    scan2<<<DS * DI / 256, 256, 0, stream>>>(Ac, Bc, Hc);
    scan3<<<dim3(2, NCH), 256, 0, stream>>>(dtf, xc, xz, dbl, A_log, Dp, Hc, ygb);
    // 9. h1 = yg @ W_out^T      [8192,256] (bf16)
    gemm_bt<16><<<dim3(128, 4), 256, 0, stream>>>(ygb, woutb, NT, DM, DI,
                                                  nullptr, nullptr, nullptr, h1b);
    // 10. h2 = h1 @ W_lin^T + b_lin + x
    gemm_bt<1 | 4 | 8><<<dim3(128, 4), 256, 0, stream>>>(h1b, wlinb, NT, DM, DM,
                                                         b_lin, x, h2, nullptr);
    // 11. ln1
    lnorm<<<NT / 4, 256, 0, stream>>>(h2, nullptr, ln1_g, ln1_b, hln, hlnb);
    // 12. ff1 = relu(hln @ W_exp^T + b_exp)  (bf16)
    gemm_bt<1 | 2 | 16><<<dim3(128, 8), 256, 0, stream>>>(hlnb, wexpb, NT, DI, DM,
                                                          b_exp, nullptr, nullptr, ff1b);
    // 13. ff2 = ff1 @ W_sq^T + b_sq
    gemm_bt<1 | 8><<<dim3(128, 4), 256, 0, stream>>>(ff1b, wsqb, NT, DM, DI,
                                                     b_sq, nullptr, ff2, nullptr);
    // 14. out = ln(hln + ff2)
    lnorm<<<NT / 4, 256, 0, stream>>>(hln, ff2, ln2_g, ln2_b, outp, nullptr);
    // 15. second output = input_states (pass-through)
    hipMemcpyAsync(outp + (size_t)NT * DM, x, (size_t)NT * DM * sizeof(float),
                   hipMemcpyDeviceToDevice, stream);
}

// Round 2
// 291.990 us; speedup vs baseline: 1.0647x; 1.0647x over previous
//
#include <hip/hip_runtime.h>
#include <stdint.h>

#define NT 8192      // sequence length
#define DM 256       // d_model
#define DI 512       // d_inner
#define DS 16        // d_state
#define DR 16        // dt_rank
#define NCH 256      // scan chunks
#define LCH 32       // chunk length (NCH*LCH == NT)
#define NSUP 16      // super-chunks
#define CPS 16       // chunks per super-chunk

typedef __bf16 bf16_t;
typedef bf16_t bf16x8 __attribute__((ext_vector_type(8)));
typedef float f32x4 __attribute__((ext_vector_type(4)));

// ---------- helpers ----------
__device__ __forceinline__ unsigned short f2b(float f) {
    union { float f; unsigned int i; } v; v.f = f;
    unsigned int r = v.i + 0x7fffu + ((v.i >> 16) & 1u);   // RNE
    return (unsigned short)(r >> 16);
}
__device__ __forceinline__ bf16x8 ld_frag_lds(const unsigned short* p) {
    union { uint4 u; bf16x8 b; } v;
    v.u = *(const uint4*)p;
    return v.b;
}
// async global->LDS, 16B per lane. LDS side must be base + lane*16 contiguous.
__device__ __forceinline__ void async16(const unsigned short* g, unsigned short* l) {
    __builtin_amdgcn_global_load_lds(
        (const __attribute__((address_space(1))) unsigned int*)g,
        (__attribute__((address_space(3))) unsigned int*)l, 16, 0, 0);
}

// ---------- fp32 -> bf16 conversion for x + 6 weight matrices ----------
struct CvtArgs {
    const float* src[7];
    unsigned short* dst[7];
    int cnt[7];
    int total;
};
__global__ __launch_bounds__(256) void cvt_all(CvtArgs a) {
    int i = blockIdx.x * 256 + threadIdx.x;
    if (i >= a.total) return;
    #pragma unroll
    for (int s = 0; s < 7; s++) {
        if (i < a.cnt[s]) { a.dst[s][i] = f2b(a.src[s][i]); return; }
        i -= a.cnt[s];
    }
}

// ---------- m97-style MFMA GEMM: C[M,N] = A[M,K] @ B[N,K]^T (+epilogue) ----------
// BK=64, global_load_lds width-16 staging, single-buffered 2-barrier K-loop.
// FLAGS: 1=bias  2=relu  4=residual(+resid[m*N+n])  8=store f32  16=store bf16
template<int BM, int BN, int FLAGS>
__global__ __launch_bounds__(256) void gemm_lds(
    const unsigned short* __restrict__ A, const unsigned short* __restrict__ B,
    int M, int N, int K,
    const float* __restrict__ bias, const float* __restrict__ resid,
    float* __restrict__ Cf, unsigned short* __restrict__ Cb)
{
    constexpr int MI = BM / 32;   // 16x16 m-frags per wave
    constexpr int NJ = BN / 32;   // 16x16 n-frags per wave
    __shared__ unsigned short sA[BM * 64];   // row-major, NO pad (global_load_lds)
    __shared__ unsigned short sB[BN * 64];
    const int tid = threadIdx.x;
    const int m0 = blockIdx.x * BM;
    const int n0 = blockIdx.y * BN;
    const int wave = tid >> 6, lane = tid & 63;
    const int wm = (wave & 1) * (BM / 2);
    const int wn = (wave >> 1) * (BN / 2);
    const int qm = lane >> 4, rm = lane & 15;

    f32x4 acc[MI][NJ];
    #pragma unroll
    for (int i = 0; i < MI; i++)
        #pragma unroll
        for (int j = 0; j < NJ; j++)
            #pragma unroll
            for (int r = 0; r < 4; r++) acc[i][j][r] = 0.f;

    const int sr = tid >> 3;          // staging row within 32-row group
    const int sc = (tid & 7) * 8;     // staging col (elements)

    for (int k0 = 0; k0 < K; k0 += 64) {
        __syncthreads();
        #pragma unroll
        for (int j = 0; j < BM / 32; j++) {
            int r = sr + j * 32;
            async16(A + (size_t)(m0 + r) * K + k0 + sc, &sA[r * 64 + sc]);
        }
        #pragma unroll
        for (int j = 0; j < BN / 32; j++) {
            int r = sr + j * 32;
            if (n0 + r < N)   // OOB rows leave LDS garbage; cols guarded at store
                async16(B + (size_t)(n0 + r) * K + k0 + sc, &sB[r * 64 + sc]);
        }
        __syncthreads();   // drains vmcnt(0) -> staged data visible
        #pragma unroll
        for (int ks = 0; ks < 64; ks += 32) {
            bf16x8 af[MI], bfr[NJ];
            #pragma unroll
            for (int i = 0; i < MI; i++)
                af[i] = ld_frag_lds(&sA[(wm + i * 16 + rm) * 64 + ks + qm * 8]);
            #pragma unroll
            for (int j = 0; j < NJ; j++)
                bfr[j] = ld_frag_lds(&sB[(wn + j * 16 + rm) * 64 + ks + qm * 8]);
            #pragma unroll
            for (int i = 0; i < MI; i++)
                #pragma unroll
                for (int j = 0; j < NJ; j++)
                    acc[i][j] = __builtin_amdgcn_mfma_f32_16x16x32_bf16(
                        af[i], bfr[j], acc[i][j], 0, 0, 0);
        }
    }

    // epilogue: D[m][n]: n = lane&15, m = (lane>>4)*4 + reg   [m89-verified]
    #pragma unroll
    for (int i = 0; i < MI; i++) {
        int mrow = m0 + wm + i * 16 + qm * 4;
        #pragma unroll
        for (int j = 0; j < NJ; j++) {
            int ncol = n0 + wn + j * 16 + rm;
            if (ncol < N) {
                #pragma unroll
                for (int r = 0; r < 4; r++) {
                    float v = acc[i][j][r];
                    int mm = mrow + r;
                    if constexpr (FLAGS & 1) v += bias[ncol];
                    if constexpr (FLAGS & 4) v += resid[(size_t)mm * N + ncol];
                    if constexpr (FLAGS & 2) v = v > 0.f ? v : 0.f;
                    if constexpr (FLAGS & 8) Cf[(size_t)mm * N + ncol] = v;
                    if constexpr (FLAGS & 16) Cb[(size_t)mm * N + ncol] = f2b(v);
                }
            }
        }
    }
}

// ---------- depthwise causal conv (k=4) + SiLU ----------
__global__ __launch_bounds__(256) void conv_silu(
    const float* __restrict__ xz, const float* __restrict__ cw,
    const float* __restrict__ cb, float* __restrict__ xc,
    unsigned short* __restrict__ xcb)
{
    int idx = blockIdx.x * 256 + threadIdx.x;   // t*DI + d
    int d = idx & (DI - 1), t = idx >> 9;
    float v = cb[d];
    #pragma unroll
    for (int k = 0; k < 4; k++) {
        int tt = t - 3 + k;
        if (tt >= 0) v += xz[(size_t)tt * 1024 + d] * cw[d * 4 + k];
    }
    float s = v / (1.f + __expf(-v));
    xc[idx] = s;
    xcb[idx] = f2b(s);
}

// ---------- scan phase 1 (dt fused): per-chunk decay product + local end ----------
__global__ __launch_bounds__(256) void scan1(
    const float* __restrict__ dbl, const float* __restrict__ Wdt,
    const float* __restrict__ bdt, const float* __restrict__ xc,
    const float* __restrict__ A_log, float* __restrict__ dt,
    float* __restrict__ Ac, float* __restrict__ Bc)
{
    __shared__ float sD[LCH][DR];
    __shared__ float sB[LCH][DS];
    const int d = blockIdx.x * 256 + threadIdx.x;  // 0..511
    const int c = blockIdx.y;
    const int t0 = c * LCH;
    for (int e = threadIdx.x; e < LCH * 32; e += 256) {
        int tt = e >> 5, col = e & 31;
        float v = dbl[(size_t)(t0 + tt) * 48 + col];
        if (col < DR) sD[tt][col] = v; else sB[tt][col - DR] = v;
    }
    __syncthreads();
    float w[DR];
    #pragma unroll
    for (int j = 0; j < DR; j++) w[j] = Wdt[d * DR + j];
    const float bd = bdt[d];
    float A[DS], h[DS];
    #pragma unroll
    for (int s = 0; s < DS; s++) { A[s] = -__expf(A_log[d * DS + s]); h[s] = 0.f; }
    float sumdt = 0.f;
    for (int t = 0; t < LCH; t++) {
        float accd = bd;
        #pragma unroll
        for (int j = 0; j < DR; j++) accd += sD[t][j] * w[j];
        float dtv = accd > 20.f ? accd : log1pf(__expf(accd));
        dt[(size_t)(t0 + t) * DI + d] = dtv;
        float xcv = xc[(size_t)(t0 + t) * DI + d];
        float dtx = dtv * xcv;
        sumdt += dtv;
        #pragma unroll
        for (int s = 0; s < DS; s++)
            h[s] = __expf(dtv * A[s]) * h[s] + dtx * sB[t][s];
    }
    #pragma unroll
    for (int s = 0; s < DS; s++) {
        size_t off = ((size_t)c * DS + s) * DI + d;
        Ac[off] = __expf(sumdt * A[s]);   // == prod_t exp(dt_t*A)
        Bc[off] = h[s];
    }
}

// ---------- scan phase 2a: per-super-chunk local scan (parallel over supers) ----
__global__ __launch_bounds__(256) void scan2a(
    const float* __restrict__ Ac, const float* __restrict__ Bc,
    float* __restrict__ Ap, float* __restrict__ Hl,
    float* __restrict__ Es, float* __restrict__ Ds)
{
    int p = blockIdx.x * 256 + threadIdx.x;   // (s*DI+d) 0..8191
    int j = blockIdx.y;                        // super-chunk 0..15
    float h = 0.f, P = 1.f;
    for (int cc = 0; cc < CPS; cc++) {
        size_t off = (size_t)(j * CPS + cc) * 8192 + p;
        Hl[off] = h; Ap[off] = P;
        float a = Ac[off];
        h = a * h + Bc[off];
        P *= a;
    }
    Es[(size_t)j * 8192 + p] = h;
    Ds[(size_t)j * 8192 + p] = P;
}

// ---------- scan phase 2b: 16-step scan over super-chunks ----------
__global__ __launch_bounds__(256) void scan2b(
    const float* __restrict__ Es, const float* __restrict__ Ds,
    float* __restrict__ Ss)
{
    int p = blockIdx.x * 256 + threadIdx.x;
    float S = 0.f;
    for (int j = 0; j < NSUP; j++) {
        Ss[(size_t)j * 8192 + p] = S;
        S = Ds[(size_t)j * 8192 + p] * S + Es[(size_t)j * 8192 + p];
    }
}

// ---------- scan phase 3: replay from composed init; fuse +Dp*xc, *silu(z) -----
__global__ __launch_bounds__(256) void scan3(
    const float* __restrict__ dt, const float* __restrict__ xc,
    const float* __restrict__ xz, const float* __restrict__ dbl,
    const float* __restrict__ A_log, const float* __restrict__ Dp,
    const float* __restrict__ Ap, const float* __restrict__ Hl,
    const float* __restrict__ Ss, unsigned short* __restrict__ ygb)
{
    __shared__ float sB[LCH][DS];
    __shared__ float sC[LCH][DS];
    const int d = blockIdx.x * 256 + threadIdx.x;
    const int c = blockIdx.y;
    const int jsup = c >> 4;
    const int t0 = c * LCH;
    for (int e = threadIdx.x; e < LCH * 32; e += 256) {
        int tt = e >> 5, col = e & 31;
        float v = dbl[(size_t)(t0 + tt) * 48 + DR + col];
        if (col < DS) sB[tt][col] = v; else sC[tt][col - DS] = v;
    }
    __syncthreads();
    float A[DS], h[DS];
    #pragma unroll
    for (int s = 0; s < DS; s++) {
        A[s] = -__expf(A_log[d * DS + s]);
        size_t off = (size_t)c * 8192 + s * DI + d;
        h[s] = Ap[off] * Ss[(size_t)jsup * 8192 + s * DI + d] + Hl[off];
    }
    float dpv = Dp[d];
    for (int t = 0; t < LCH; t++) {
        float dtv = dt[(size_t)(t0 + t) * DI + d];
        float xcv = xc[(size_t)(t0 + t) * DI + d];
        float zv  = xz[(size_t)(t0 + t) * 1024 + DI + d];
        float dtx = dtv * xcv;
        float y = 0.f;
        #pragma unroll
        for (int s = 0; s < DS; s++) {
            h[s] = __expf(dtv * A[s]) * h[s] + dtx * sB[t][s];
            y += h[s] * sC[t][s];
        }
        float sz = zv / (1.f + __expf(-zv));
        ygb[(size_t)(t0 + t) * DI + d] = f2b((y + dpv * xcv) * sz);
    }
}

// ---------- LayerNorm over 256 cols (one wave per row); optional add X2 ----------
__global__ __launch_bounds__(256) void lnorm(
    const float* __restrict__ X, const float* __restrict__ X2,
    const float* __restrict__ g, const float* __restrict__ b,
    float* __restrict__ outf, unsigned short* __restrict__ outb)
{
    int wave = threadIdx.x >> 6, lane = threadIdx.x & 63;
    int row = blockIdx.x * 4 + wave;
    const float* x = X + (size_t)row * DM;
    float v[4];
    #pragma unroll
    for (int i = 0; i < 4; i++) {
        int col = lane + i * 64;
        v[i] = x[col];
        if (X2) v[i] += X2[(size_t)row * DM + col];
    }
    float s = v[0] + v[1] + v[2] + v[3];
    float s2 = v[0]*v[0] + v[1]*v[1] + v[2]*v[2] + v[3]*v[3];
    #pragma unroll
    for (int m = 1; m < 64; m <<= 1) {
        s  += __shfl_xor(s, m, 64);
        s2 += __shfl_xor(s2, m, 64);
    }
    float mean = s * (1.f / DM);
    float var = s2 * (1.f / DM) - mean * mean;
    float inv = rsqrtf(var + 1e-5f);
    #pragma unroll
    for (int i = 0; i < 4; i++) {
        int col = lane + i * 64;
        float o = (v[i] - mean) * inv * g[col] + b[col];
        if (outf) outf[(size_t)row * DM + col] = o;
        if (outb) outb[(size_t)row * DM + col] = f2b(o);
    }
}

// ---------- workspace layout (bytes; ws_size = 256 MiB) ----------
static constexpr size_t OFF_XZ    = 0;            // f32 [8192][1024]   33554432
static constexpr size_t OFF_XC    = 33554432;     // f32 [8192][512]    16777216
static constexpr size_t OFF_XCB   = 50331648;     // bf16 [8192][512]    8388608
static constexpr size_t OFF_DBL   = 58720256;     // f32 [8192][48]      1572864
static constexpr size_t OFF_DT    = 60293120;     // f32 [8192][512]    16777216
static constexpr size_t OFF_AC    = 77070336;     // f32 [256][16][512]  8388608
static constexpr size_t OFF_BC    = 85458944;     // f32                 8388608
static constexpr size_t OFF_HL    = 93847552;     // f32 [256][8192]     8388608
static constexpr size_t OFF_AP    = 102236160;    // f32 [256][8192]     8388608
static constexpr size_t OFF_YGB   = 110624768;    // bf16 [8192][512]    8388608
static constexpr size_t OFF_XB    = 119013376;    // bf16 [8192][256]    4194304
static constexpr size_t OFF_ES    = 123207680;    // f32 [16][8192]       524288
static constexpr size_t OFF_DS2   = 123731968;    // f32 [16][8192]       524288
static constexpr size_t OFF_SS    = 124256256;    // f32 [16][8192]       524288
static constexpr size_t OFF_WINB  = 124780544;    // bf16 [1024][256]     524288
static constexpr size_t OFF_WXB   = 125304832;    // bf16 [48][512]        49152
static constexpr size_t OFF_WOUTB = 125353984;    // bf16 [256][512]      262144
static constexpr size_t OFF_WLINB = 125616128;    // bf16 [256][256]      131072
static constexpr size_t OFF_WEXPB = 125747200;    // bf16 [512][256]      262144
static constexpr size_t OFF_WSQB  = 126009344;    // bf16 [256][512]      262144
// aliases (safe: xz/xc/dt dead after scan3)
static constexpr size_t OFF_H1B   = OFF_XZ;                // bf16 [8192][256]
static constexpr size_t OFF_H2    = OFF_XZ + 4194304;      // f32  [8192][256]
static constexpr size_t OFF_HLN   = OFF_XZ + 12582912;     // f32  [8192][256]
static constexpr size_t OFF_HLNB  = OFF_XZ + 20971520;     // bf16 [8192][256]
static constexpr size_t OFF_FF1B  = OFF_DT;                // bf16 [8192][512]
static constexpr size_t OFF_FF2   = OFF_DT + 8388608;      // f32  [8192][256]

extern "C" void kernel_launch(void* const* d_in, const int* in_sizes, int n_in,
                              void* d_out, int out_size, void* d_ws, size_t ws_size,
                              hipStream_t stream)
{
    const float* x      = (const float*)d_in[0];
    const float* W_in   = (const float*)d_in[2];
    const float* conv_w = (const float*)d_in[3];
    const float* conv_b = (const float*)d_in[4];
    const float* W_x    = (const float*)d_in[5];
    const float* W_dt   = (const float*)d_in[6];
    const float* b_dt   = (const float*)d_in[7];
    const float* A_log  = (const float*)d_in[8];
    const float* Dp     = (const float*)d_in[9];
    const float* W_out  = (const float*)d_in[10];
    const float* W_lin  = (const float*)d_in[11];
    const float* b_lin  = (const float*)d_in[12];
    const float* ln1_g  = (const float*)d_in[13];
    const float* ln1_b  = (const float*)d_in[14];
    const float* W_exp  = (const float*)d_in[15];
    const float* b_exp  = (const float*)d_in[16];
    const float* W_sq   = (const float*)d_in[17];
    const float* b_sq   = (const float*)d_in[18];
    const float* ln2_g  = (const float*)d_in[19];
    const float* ln2_b  = (const float*)d_in[20];

    char* ws = (char*)d_ws;
    float* xz   = (float*)(ws + OFF_XZ);
    float* xc   = (float*)(ws + OFF_XC);
    unsigned short* xcb = (unsigned short*)(ws + OFF_XCB);
    float* dbl  = (float*)(ws + OFF_DBL);
    float* dtf  = (float*)(ws + OFF_DT);
    float* Ac   = (float*)(ws + OFF_AC);
    float* Bc   = (float*)(ws + OFF_BC);
    float* Hl   = (float*)(ws + OFF_HL);
    float* Ap   = (float*)(ws + OFF_AP);
    float* Es   = (float*)(ws + OFF_ES);
    float* Ds   = (float*)(ws + OFF_DS2);
    float* Ss   = (float*)(ws + OFF_SS);
    unsigned short* ygb   = (unsigned short*)(ws + OFF_YGB);
    unsigned short* xb    = (unsigned short*)(ws + OFF_XB);
    unsigned short* winb  = (unsigned short*)(ws + OFF_WINB);
    unsigned short* wxb   = (unsigned short*)(ws + OFF_WXB);
    unsigned short* woutb = (unsigned short*)(ws + OFF_WOUTB);
    unsigned short* wlinb = (unsigned short*)(ws + OFF_WLINB);
    unsigned short* wexpb = (unsigned short*)(ws + OFF_WEXPB);
    unsigned short* wsqb  = (unsigned short*)(ws + OFF_WSQB);
    unsigned short* h1b   = (unsigned short*)(ws + OFF_H1B);
    float* h2   = (float*)(ws + OFF_H2);
    float* hln  = (float*)(ws + OFF_HLN);
    unsigned short* hlnb  = (unsigned short*)(ws + OFF_HLNB);
    unsigned short* ff1b  = (unsigned short*)(ws + OFF_FF1B);
    float* ff2  = (float*)(ws + OFF_FF2);
    float* outp = (float*)d_out;

    // 1. bf16 conversions
    CvtArgs ca;
    ca.src[0] = x;     ca.dst[0] = xb;    ca.cnt[0] = NT * DM;
    ca.src[1] = W_in;  ca.dst[1] = winb;  ca.cnt[1] = 1024 * DM;
    ca.src[2] = W_x;   ca.dst[2] = wxb;   ca.cnt[2] = 48 * DI;
    ca.src[3] = W_out; ca.dst[3] = woutb; ca.cnt[3] = DM * DI;
    ca.src[4] = W_lin; ca.dst[4] = wlinb; ca.cnt[4] = DM * DM;
    ca.src[5] = W_exp; ca.dst[5] = wexpb; ca.cnt[5] = DI * DM;
    ca.src[6] = W_sq;  ca.dst[6] = wsqb;  ca.cnt[6] = DM * DI;
    ca.total = ca.cnt[0]+ca.cnt[1]+ca.cnt[2]+ca.cnt[3]+ca.cnt[4]+ca.cnt[5]+ca.cnt[6];
    cvt_all<<<(ca.total + 255) / 256, 256, 0, stream>>>(ca);

    // 2. xz = x @ W_in^T        [8192,1024]
    gemm_lds<128,128,8><<<dim3(64, 8), 256, 0, stream>>>(xb, winb, NT, 1024, DM,
                                                         nullptr, nullptr, xz, nullptr);
    // 3. causal depthwise conv + silu
    conv_silu<<<NT * DI / 256, 256, 0, stream>>>(xz, conv_w, conv_b, xc, xcb);
    // 4. dbl = xc @ W_x^T       [8192,48]
    gemm_lds<128,64,8><<<dim3(64, 1), 256, 0, stream>>>(xcb, wxb, NT, 48, DI,
                                                        nullptr, nullptr, dbl, nullptr);
    // 5-8. chunked selective scan (dt fused into scan1)
    scan1<<<dim3(2, NCH), 256, 0, stream>>>(dbl, W_dt, b_dt, xc, A_log, dtf, Ac, Bc);
    scan2a<<<dim3(32, NSUP), 256, 0, stream>>>(Ac, Bc, Ap, Hl, Es, Ds);
    scan2b<<<32, 256, 0, stream>>>(Es, Ds, Ss);
    scan3<<<dim3(2, NCH), 256, 0, stream>>>(dtf, xc, xz, dbl, A_log, Dp, Ap, Hl, Ss, ygb);
    // 9. h1 = yg @ W_out^T      [8192,256] (bf16)
    gemm_lds<64,128,16><<<dim3(128, 2), 256, 0, stream>>>(ygb, woutb, NT, DM, DI,
                                                          nullptr, nullptr, nullptr, h1b);
    // 10. h2 = h1 @ W_lin^T + b_lin + x
    gemm_lds<64,128,1|4|8><<<dim3(128, 2), 256, 0, stream>>>(h1b, wlinb, NT, DM, DM,
                                                             b_lin, x, h2, nullptr);
    // 11. ln1
    lnorm<<<NT / 4, 256, 0, stream>>>(h2, nullptr, ln1_g, ln1_b, hln, hlnb);
    // 12. ff1 = relu(hln @ W_exp^T + b_exp)  (bf16)
    gemm_lds<128,128,1|2|16><<<dim3(64, 4), 256, 0, stream>>>(hlnb, wexpb, NT, DI, DM,
                                                              b_exp, nullptr, nullptr, ff1b);
    // 13. ff2 = ff1 @ W_sq^T + b_sq
    gemm_lds<64,128,1|8><<<dim3(128, 2), 256, 0, stream>>>(ff1b, wsqb, NT, DM, DI,
                                                           b_sq, nullptr, ff2, nullptr);
    // 14. out = ln(hln + ff2)
    lnorm<<<NT / 4, 256, 0, stream>>>(hln, ff2, ln2_g, ln2_b, outp, nullptr);
    // 15. second output = input_states (pass-through)
    hipMemcpyAsync(outp + (size_t)NT * DM, x, (size_t)NT * DM * sizeof(float),
                   hipMemcpyDeviceToDevice, stream);
}

// Round 3
// 289.380 us; speedup vs baseline: 1.0743x; 1.0090x over previous
//
#include <hip/hip_runtime.h>
#include <stdint.h>

#define NT 8192      // sequence length
#define DM 256       // d_model
#define DI 512       // d_inner
#define DS 16        // d_state
#define DR 16        // dt_rank
#define NCH 512      // scan chunks
#define LCH 16       // chunk length (NCH*LCH == NT)
#define NSUP 32      // super-chunks
#define CPS 16       // chunks per super-chunk (NSUP*CPS == NCH)

typedef __bf16 bf16_t;
typedef bf16_t bf16x8 __attribute__((ext_vector_type(8)));
typedef float f32x4 __attribute__((ext_vector_type(4)));

// ---------- helpers ----------
__device__ __forceinline__ unsigned short f2b(float f) {
    union { float f; unsigned int i; } v; v.f = f;
    unsigned int r = v.i + 0x7fffu + ((v.i >> 16) & 1u);   // RNE
    return (unsigned short)(r >> 16);
}
__device__ __forceinline__ bf16x8 ld_frag_lds(const unsigned short* p) {
    union { uint4 u; bf16x8 b; } v;
    v.u = *(const uint4*)p;
    return v.b;
}
// async global->LDS, 16B per lane. LDS side must be base + lane*16 contiguous.
__device__ __forceinline__ void async16(const unsigned short* g, unsigned short* l) {
    __builtin_amdgcn_global_load_lds(
        (const __attribute__((address_space(1))) unsigned int*)g,
        (__attribute__((address_space(3))) unsigned int*)l, 16, 0, 0);
}
__device__ __forceinline__ float fast_softplus(float x) {
    // log(1+e^x); safe: e^x overflows only past x~88, branch at 20
    return x > 20.f ? x : __logf(1.f + __expf(x));
}
__device__ __forceinline__ float silu(float x) {
    return x / (1.f + __expf(-x));
}

// ---------- fp32 -> bf16 conversion for x + 6 weight matrices ----------
struct CvtArgs {
    const float* src[7];
    unsigned short* dst[7];
    int cnt[7];
    int total;
};
__global__ __launch_bounds__(256) void cvt_all(CvtArgs a) {
    int i = blockIdx.x * 256 + threadIdx.x;
    if (i >= a.total) return;
    #pragma unroll
    for (int s = 0; s < 7; s++) {
        if (i < a.cnt[s]) { a.dst[s][i] = f2b(a.src[s][i]); return; }
        i -= a.cnt[s];
    }
}

// ---------- m97-style MFMA GEMM: C[M,N] = A[M,K] @ B[N,K]^T (+epilogue) ----------
// FLAGS: 1=bias  2=relu  4=residual(+resid[m*N+n])  8=store f32  16=store bf16
template<int BM, int BN, int FLAGS>
__global__ __launch_bounds__(256) void gemm_lds(
    const unsigned short* __restrict__ A, const unsigned short* __restrict__ B,
    int M, int N, int K,
    const float* __restrict__ bias, const float* __restrict__ resid,
    float* __restrict__ Cf, unsigned short* __restrict__ Cb)
{
    constexpr int MI = BM / 32;
    constexpr int NJ = BN / 32;
    __shared__ unsigned short sA[BM * 64];   // row-major, NO pad (global_load_lds)
    __shared__ unsigned short sB[BN * 64];
    const int tid = threadIdx.x;
    const int m0 = blockIdx.x * BM;
    const int n0 = blockIdx.y * BN;
    const int wave = tid >> 6, lane = tid & 63;
    const int wm = (wave & 1) * (BM / 2);
    const int wn = (wave >> 1) * (BN / 2);
    const int qm = lane >> 4, rm = lane & 15;

    f32x4 acc[MI][NJ];
    #pragma unroll
    for (int i = 0; i < MI; i++)
        #pragma unroll
        for (int j = 0; j < NJ; j++)
            #pragma unroll
            for (int r = 0; r < 4; r++) acc[i][j][r] = 0.f;

    const int sr = tid >> 3;
    const int sc = (tid & 7) * 8;

    for (int k0 = 0; k0 < K; k0 += 64) {
        __syncthreads();
        #pragma unroll
        for (int j = 0; j < BM / 32; j++) {
            int r = sr + j * 32;
            async16(A + (size_t)(m0 + r) * K + k0 + sc, &sA[r * 64 + sc]);
        }
        #pragma unroll
        for (int j = 0; j < BN / 32; j++) {
            int r = sr + j * 32;
            if (n0 + r < N)
                async16(B + (size_t)(n0 + r) * K + k0 + sc, &sB[r * 64 + sc]);
        }
        __syncthreads();
        #pragma unroll
        for (int ks = 0; ks < 64; ks += 32) {
            bf16x8 af[MI], bfr[NJ];
            #pragma unroll
            for (int i = 0; i < MI; i++)
                af[i] = ld_frag_lds(&sA[(wm + i * 16 + rm) * 64 + ks + qm * 8]);
            #pragma unroll
            for (int j = 0; j < NJ; j++)
                bfr[j] = ld_frag_lds(&sB[(wn + j * 16 + rm) * 64 + ks + qm * 8]);
            #pragma unroll
            for (int i = 0; i < MI; i++)
                #pragma unroll
                for (int j = 0; j < NJ; j++)
                    acc[i][j] = __builtin_amdgcn_mfma_f32_16x16x32_bf16(
                        af[i], bfr[j], acc[i][j], 0, 0, 0);
        }
    }

    // epilogue: D[m][n]: n = lane&15, m = (lane>>4)*4 + reg   [m89-verified]
    #pragma unroll
    for (int i = 0; i < MI; i++) {
        int mrow = m0 + wm + i * 16 + qm * 4;
        #pragma unroll
        for (int j = 0; j < NJ; j++) {
            int ncol = n0 + wn + j * 16 + rm;
            if (ncol < N) {
                #pragma unroll
                for (int r = 0; r < 4; r++) {
                    float v = acc[i][j][r];
                    int mm = mrow + r;
                    if constexpr (FLAGS & 1) v += bias[ncol];
                    if constexpr (FLAGS & 4) v += resid[(size_t)mm * N + ncol];
                    if constexpr (FLAGS & 2) v = v > 0.f ? v : 0.f;
                    if constexpr (FLAGS & 8) Cf[(size_t)mm * N + ncol] = v;
                    if constexpr (FLAGS & 16) Cb[(size_t)mm * N + ncol] = f2b(v);
                }
            }
        }
    }
}

// ---------- depthwise causal conv (k=4) + SiLU -> bf16 only (for W_x gemm) ----
__global__ __launch_bounds__(256) void conv_silu_b(
    const float* __restrict__ xz, const float* __restrict__ cw,
    const float* __restrict__ cb, unsigned short* __restrict__ xcb)
{
    int idx = blockIdx.x * 256 + threadIdx.x;   // t*DI + d
    int d = idx & (DI - 1), t = idx >> 9;
    float v = cb[d];
    #pragma unroll
    for (int k = 0; k < 4; k++) {
        int tt = t - 3 + k;
        if (tt >= 0) v += xz[(size_t)tt * 1024 + d] * cw[d * 4 + k];
    }
    xcb[idx] = f2b(silu(v));
}

// ---------- scan phase 1: conv+dt fused; per-chunk decay product + local end ----
__global__ __launch_bounds__(256, 4) void scan1(
    const float* __restrict__ xz, const float* __restrict__ cw,
    const float* __restrict__ cbp, const float* __restrict__ dbl,
    const float* __restrict__ Wdt, const float* __restrict__ bdt,
    const float* __restrict__ A_log,
    float* __restrict__ Ac, float* __restrict__ Bc)
{
    __shared__ float sR[LCH * 48];   // chunk's dbl rows (contiguous copy)
    const int d = blockIdx.x * 256 + threadIdx.x;  // 0..511
    const int c = blockIdx.y;
    const int t0 = c * LCH;
    {   // LCH*48 = 768 floats = 192 float4, contiguous in dbl
        const float4* src = (const float4*)(dbl + (size_t)t0 * 48);
        if (threadIdx.x < 192) ((float4*)sR)[threadIdx.x] = src[threadIdx.x];
    }
    __syncthreads();
    const float cw0 = cw[d*4], cw1 = cw[d*4+1], cw2 = cw[d*4+2], cw3 = cw[d*4+3];
    const float cb = cbp[d];
    const float* xzp = xz + d;
    float x0 = (t0 >= 3) ? xzp[(size_t)(t0-3) * 1024] : 0.f;
    float x1 = (t0 >= 2) ? xzp[(size_t)(t0-2) * 1024] : 0.f;
    float x2 = (t0 >= 1) ? xzp[(size_t)(t0-1) * 1024] : 0.f;
    float w[DR], A[DS], h[DS];
    #pragma unroll
    for (int j = 0; j < DR; j++) w[j] = Wdt[d * DR + j];
    const float bd = bdt[d];
    #pragma unroll
    for (int s = 0; s < DS; s++) { A[s] = -__expf(A_log[d * DS + s]); h[s] = 0.f; }
    float sumdt = 0.f;
    #pragma unroll 4
    for (int t = 0; t < LCH; t++) {
        float x3 = xzp[(size_t)(t0 + t) * 1024];
        float cv = cb + x0 * cw0 + x1 * cw1 + x2 * cw2 + x3 * cw3;
        x0 = x1; x1 = x2; x2 = x3;
        float xcv = silu(cv);
        const float* r = &sR[t * 48];
        float4 rd[4], rb[4];
        #pragma unroll
        for (int k = 0; k < 4; k++) { rd[k] = ((const float4*)r)[k]; rb[k] = ((const float4*)r)[4 + k]; }
        float accd = bd;
        #pragma unroll
        for (int k = 0; k < 4; k++)
            accd += rd[k].x * w[4*k] + rd[k].y * w[4*k+1] + rd[k].z * w[4*k+2] + rd[k].w * w[4*k+3];
        float dtv = fast_softplus(accd);
        sumdt += dtv;
        float dtx = dtv * xcv;
        const float* bptr = (const float*)rb;
        #pragma unroll
        for (int s = 0; s < DS; s++)
            h[s] = __expf(dtv * A[s]) * h[s] + dtx * bptr[s];
    }
    #pragma unroll
    for (int s = 0; s < DS; s++) {
        size_t off = ((size_t)c * DS + s) * DI + d;
        Ac[off] = __expf(sumdt * A[s]);
        Bc[off] = h[s];
    }
}

// ---------- scan phase 2a: per-super-chunk local scan ----------
__global__ __launch_bounds__(256) void scan2a(
    const float* __restrict__ Ac, const float* __restrict__ Bc,
    float* __restrict__ Ap, float* __restrict__ Hl,
    float* __restrict__ Es, float* __restrict__ Ds)
{
    int p = blockIdx.x * 256 + threadIdx.x;   // (s*DI+d) 0..8191
    int j = blockIdx.y;                        // super-chunk 0..NSUP-1
    float h = 0.f, P = 1.f;
    for (int cc = 0; cc < CPS; cc++) {
        size_t off = (size_t)(j * CPS + cc) * 8192 + p;
        Hl[off] = h; Ap[off] = P;
        float a = Ac[off];
        h = a * h + Bc[off];
        P *= a;
    }
    Es[(size_t)j * 8192 + p] = h;
    Ds[(size_t)j * 8192 + p] = P;
}

// ---------- scan phase 2b: NSUP-step scan over super-chunks ----------
__global__ __launch_bounds__(256) void scan2b(
    const float* __restrict__ Es, const float* __restrict__ Ds,
    float* __restrict__ Ss)
{
    int p = blockIdx.x * 256 + threadIdx.x;
    float S = 0.f;
    for (int j = 0; j < NSUP; j++) {
        Ss[(size_t)j * 8192 + p] = S;
        S = Ds[(size_t)j * 8192 + p] * S + Es[(size_t)j * 8192 + p];
    }
}

// ---------- scan phase 3: replay (conv+dt recomputed); fuse +Dp*xc, *silu(z) ---
__global__ __launch_bounds__(256, 4) void scan3(
    const float* __restrict__ xz, const float* __restrict__ cw,
    const float* __restrict__ cbp, const float* __restrict__ dbl,
    const float* __restrict__ Wdt, const float* __restrict__ bdt,
    const float* __restrict__ A_log, const float* __restrict__ Dpp,
    const float* __restrict__ Ap, const float* __restrict__ Hl,
    const float* __restrict__ Ss, unsigned short* __restrict__ ygb)
{
    __shared__ float sR[LCH * 48];
    const int d = blockIdx.x * 256 + threadIdx.x;
    const int c = blockIdx.y;
    const int jsup = c / CPS;
    const int t0 = c * LCH;
    {
        const float4* src = (const float4*)(dbl + (size_t)t0 * 48);
        if (threadIdx.x < 192) ((float4*)sR)[threadIdx.x] = src[threadIdx.x];
    }
    __syncthreads();
    const float cw0 = cw[d*4], cw1 = cw[d*4+1], cw2 = cw[d*4+2], cw3 = cw[d*4+3];
    const float cb = cbp[d];
    const float* xzp = xz + d;
    const float* zp  = xz + DI + d;
    float x0 = (t0 >= 3) ? xzp[(size_t)(t0-3) * 1024] : 0.f;
    float x1 = (t0 >= 2) ? xzp[(size_t)(t0-2) * 1024] : 0.f;
    float x2 = (t0 >= 1) ? xzp[(size_t)(t0-1) * 1024] : 0.f;
    float w[DR], A[DS], h[DS];
    #pragma unroll
    for (int j = 0; j < DR; j++) w[j] = Wdt[d * DR + j];
    const float bd = bdt[d];
    const float dpv = Dpp[d];
    #pragma unroll
    for (int s = 0; s < DS; s++) {
        A[s] = -__expf(A_log[d * DS + s]);
        size_t off = (size_t)c * 8192 + s * DI + d;
        h[s] = Ap[off] * Ss[(size_t)jsup * 8192 + s * DI + d] + Hl[off];
    }
    #pragma unroll 4
    for (int t = 0; t < LCH; t++) {
        float x3 = xzp[(size_t)(t0 + t) * 1024];
        float zv = zp[(size_t)(t0 + t) * 1024];
        float cv = cb + x0 * cw0 + x1 * cw1 + x2 * cw2 + x3 * cw3;
        x0 = x1; x1 = x2; x2 = x3;
        float xcv = silu(cv);
        const float* r = &sR[t * 48];
        float4 rd[4], rb[4], rc[4];
        #pragma unroll
        for (int k = 0; k < 4; k++) {
            rd[k] = ((const float4*)r)[k];
            rb[k] = ((const float4*)r)[4 + k];
            rc[k] = ((const float4*)r)[8 + k];
        }
        float accd = bd;
        #pragma unroll
        for (int k = 0; k < 4; k++)
            accd += rd[k].x * w[4*k] + rd[k].y * w[4*k+1] + rd[k].z * w[4*k+2] + rd[k].w * w[4*k+3];
        float dtv = fast_softplus(accd);
        float dtx = dtv * xcv;
        const float* bptr = (const float*)rb;
        const float* cptr = (const float*)rc;
        float y = 0.f;
        #pragma unroll
        for (int s = 0; s < DS; s++) {
            h[s] = __expf(dtv * A[s]) * h[s] + dtx * bptr[s];
            y += h[s] * cptr[s];
        }
        ygb[(size_t)(t0 + t) * DI + d] = f2b((y + dpv * xcv) * silu(zv));
    }
}

// ---------- LayerNorm over 256 cols (one wave per row) ----------
// optional add X2; optional passthrough copy (csrc->cdst, same row layout)
__global__ __launch_bounds__(256) void lnorm(
    const float* __restrict__ X, const float* __restrict__ X2,
    const float* __restrict__ g, const float* __restrict__ b,
    float* __restrict__ outf, unsigned short* __restrict__ outb,
    const float* __restrict__ csrc, float* __restrict__ cdst)
{
    int wave = threadIdx.x >> 6, lane = threadIdx.x & 63;
    int row = blockIdx.x * 4 + wave;
    const float* x = X + (size_t)row * DM;
    float v[4];
    #pragma unroll
    for (int i = 0; i < 4; i++) {
        int col = lane + i * 64;
        v[i] = x[col];
        if (X2) v[i] += X2[(size_t)row * DM + col];
    }
    if (cdst) {
        #pragma unroll
        for (int i = 0; i < 4; i++) {
            int col = lane + i * 64;
            cdst[(size_t)row * DM + col] = csrc[(size_t)row * DM + col];
        }
    }
    float s = v[0] + v[1] + v[2] + v[3];
    float s2 = v[0]*v[0] + v[1]*v[1] + v[2]*v[2] + v[3]*v[3];
    #pragma unroll
    for (int m = 1; m < 64; m <<= 1) {
        s  += __shfl_xor(s, m, 64);
        s2 += __shfl_xor(s2, m, 64);
    }
    float mean = s * (1.f / DM);
    float var = s2 * (1.f / DM) - mean * mean;
    float inv = rsqrtf(var + 1e-5f);
    #pragma unroll
    for (int i = 0; i < 4; i++) {
        int col = lane + i * 64;
        float o = (v[i] - mean) * inv * g[col] + b[col];
        if (outf) outf[(size_t)row * DM + col] = o;
        if (outb) outb[(size_t)row * DM + col] = f2b(o);
    }
}

// ---------- workspace layout (bytes; ws_size = 256 MiB) ----------
static constexpr size_t OFF_XZ    = 0;            // f32 [8192][1024]   33554432
static constexpr size_t OFF_XCB   = 33554432;     // bf16 [8192][512]    8388608
static constexpr size_t OFF_DBL   = 41943040;     // f32 [8192][48]      1572864
static constexpr size_t OFF_AC    = 43515904;     // f32 [512][16][512] 16777216
static constexpr size_t OFF_BC    = 60293120;     // f32                16777216
static constexpr size_t OFF_HL    = 77070336;     // f32 [512][8192]    16777216
static constexpr size_t OFF_AP    = 93847552;     // f32 [512][8192]    16777216
static constexpr size_t OFF_ES    = 110624768;    // f32 [32][8192]      1048576
static constexpr size_t OFF_DS2   = 111673344;    // f32 [32][8192]      1048576
static constexpr size_t OFF_SS    = 112721920;    // f32 [32][8192]      1048576
static constexpr size_t OFF_YGB   = 113770496;    // bf16 [8192][512]    8388608
static constexpr size_t OFF_XB    = 122159104;    // bf16 [8192][256]    4194304
static constexpr size_t OFF_WINB  = 126353408;    // bf16 [1024][256]     524288
static constexpr size_t OFF_WXB   = 126877696;    // bf16 [48][512]        49152
static constexpr size_t OFF_WOUTB = 126926848;    // bf16 [256][512]      262144
static constexpr size_t OFF_WLINB = 127188992;    // bf16 [256][256]      131072
static constexpr size_t OFF_WEXPB = 127320064;    // bf16 [512][256]      262144
static constexpr size_t OFF_WSQB  = 127582208;    // bf16 [256][512]      262144
// aliases (producer runs strictly after the aliased array's last reader)
static constexpr size_t OFF_H1B   = OFF_AC;                // bf16 [8192][256] (Ac dead after scan2a)
static constexpr size_t OFF_H2    = OFF_AC + 4194304;      // f32  [8192][256]
static constexpr size_t OFF_HLN   = OFF_BC;                // f32  [8192][256] (Bc dead after scan2a)
static constexpr size_t OFF_HLNB  = OFF_BC + 8388608;      // bf16 [8192][256]
static constexpr size_t OFF_FF1B  = OFF_HL;                // bf16 [8192][512] (Hl dead after scan3)
static constexpr size_t OFF_FF2   = OFF_AP;                // f32  [8192][256] (Ap dead after scan3)

extern "C" void kernel_launch(void* const* d_in, const int* in_sizes, int n_in,
                              void* d_out, int out_size, void* d_ws, size_t ws_size,
                              hipStream_t stream)
{
    const float* x      = (const float*)d_in[0];
    const float* W_in   = (const float*)d_in[2];
    const float* conv_w = (const float*)d_in[3];
    const float* conv_b = (const float*)d_in[4];
    const float* W_x    = (const float*)d_in[5];
    const float* W_dt   = (const float*)d_in[6];
    const float* b_dt   = (const float*)d_in[7];
    const float* A_log  = (const float*)d_in[8];
    const float* Dp     = (const float*)d_in[9];
    const float* W_out  = (const float*)d_in[10];
    const float* W_lin  = (const float*)d_in[11];
    const float* b_lin  = (const float*)d_in[12];
    const float* ln1_g  = (const float*)d_in[13];
    const float* ln1_b  = (const float*)d_in[14];
    const float* W_exp  = (const float*)d_in[15];
    const float* b_exp  = (const float*)d_in[16];
    const float* W_sq   = (const float*)d_in[17];
    const float* b_sq   = (const float*)d_in[18];
    const float* ln2_g  = (const float*)d_in[19];
    const float* ln2_b  = (const float*)d_in[20];

    char* ws = (char*)d_ws;
    float* xz   = (float*)(ws + OFF_XZ);
    unsigned short* xcb = (unsigned short*)(ws + OFF_XCB);
    float* dbl  = (float*)(ws + OFF_DBL);
    float* Ac   = (float*)(ws + OFF_AC);
    float* Bc   = (float*)(ws + OFF_BC);
    float* Hl   = (float*)(ws + OFF_HL);
    float* Ap   = (float*)(ws + OFF_AP);
    float* Es   = (float*)(ws + OFF_ES);
    float* Ds   = (float*)(ws + OFF_DS2);
    float* Ss   = (float*)(ws + OFF_SS);
    unsigned short* ygb   = (unsigned short*)(ws + OFF_YGB);
    unsigned short* xb    = (unsigned short*)(ws + OFF_XB);
    unsigned short* winb  = (unsigned short*)(ws + OFF_WINB);
    unsigned short* wxb   = (unsigned short*)(ws + OFF_WXB);
    unsigned short* woutb = (unsigned short*)(ws + OFF_WOUTB);
    unsigned short* wlinb = (unsigned short*)(ws + OFF_WLINB);
    unsigned short* wexpb = (unsigned short*)(ws + OFF_WEXPB);
    unsigned short* wsqb  = (unsigned short*)(ws + OFF_WSQB);
    unsigned short* h1b   = (unsigned short*)(ws + OFF_H1B);
    float* h2   = (float*)(ws + OFF_H2);
    float* hln  = (float*)(ws + OFF_HLN);
    unsigned short* hlnb  = (unsigned short*)(ws + OFF_HLNB);
    unsigned short* ff1b  = (unsigned short*)(ws + OFF_FF1B);
    float* ff2  = (float*)(ws + OFF_FF2);
    float* outp = (float*)d_out;

    // 1. bf16 conversions
    CvtArgs ca;
    ca.src[0] = x;     ca.dst[0] = xb;    ca.cnt[0] = NT * DM;
    ca.src[1] = W_in;  ca.dst[1] = winb;  ca.cnt[1] = 1024 * DM;
    ca.src[2] = W_x;   ca.dst[2] = wxb;   ca.cnt[2] = 48 * DI;
    ca.src[3] = W_out; ca.dst[3] = woutb; ca.cnt[3] = DM * DI;
    ca.src[4] = W_lin; ca.dst[4] = wlinb; ca.cnt[4] = DM * DM;
    ca.src[5] = W_exp; ca.dst[5] = wexpb; ca.cnt[5] = DI * DM;
    ca.src[6] = W_sq;  ca.dst[6] = wsqb;  ca.cnt[6] = DM * DI;
    ca.total = ca.cnt[0]+ca.cnt[1]+ca.cnt[2]+ca.cnt[3]+ca.cnt[4]+ca.cnt[5]+ca.cnt[6];
    cvt_all<<<(ca.total + 255) / 256, 256, 0, stream>>>(ca);

    // 2. xz = x @ W_in^T        [8192,1024] f32
    gemm_lds<128,128,8><<<dim3(64, 8), 256, 0, stream>>>(xb, winb, NT, 1024, DM,
                                                         nullptr, nullptr, xz, nullptr);
    // 3. conv+silu -> bf16 (only for the W_x gemm; scans recompute in f32)
    conv_silu_b<<<NT * DI / 256, 256, 0, stream>>>(xz, conv_w, conv_b, xcb);
    // 4. dbl = xc @ W_x^T       [8192,48] f32
    gemm_lds<128,64,8><<<dim3(64, 1), 256, 0, stream>>>(xcb, wxb, NT, 48, DI,
                                                        nullptr, nullptr, dbl, nullptr);
    // 5-8. chunked selective scan (conv & dt fused into scan1/scan3)
    scan1<<<dim3(2, NCH), 256, 0, stream>>>(xz, conv_w, conv_b, dbl, W_dt, b_dt,
                                            A_log, Ac, Bc);
    scan2a<<<dim3(32, NSUP), 256, 0, stream>>>(Ac, Bc, Ap, Hl, Es, Ds);
    scan2b<<<32, 256, 0, stream>>>(Es, Ds, Ss);
    scan3<<<dim3(2, NCH), 256, 0, stream>>>(xz, conv_w, conv_b, dbl, W_dt, b_dt,
                                            A_log, Dp, Ap, Hl, Ss, ygb);
    // 9. h1 = yg @ W_out^T      [8192,256] bf16
    gemm_lds<64,128,16><<<dim3(128, 2), 256, 0, stream>>>(ygb, woutb, NT, DM, DI,
                                                          nullptr, nullptr, nullptr, h1b);
    // 10. h2 = h1 @ W_lin^T + b_lin + x
    gemm_lds<64,128,1|4|8><<<dim3(128, 2), 256, 0, stream>>>(h1b, wlinb, NT, DM, DM,
                                                             b_lin, x, h2, nullptr);
    // 11. ln1
    lnorm<<<NT / 4, 256, 0, stream>>>(h2, nullptr, ln1_g, ln1_b, hln, hlnb,
                                      nullptr, nullptr);
    // 12. ff1 = relu(hln @ W_exp^T + b_exp)  bf16
    gemm_lds<128,128,1|2|16><<<dim3(64, 4), 256, 0, stream>>>(hlnb, wexpb, NT, DI, DM,
                                                              b_exp, nullptr, nullptr, ff1b);
    // 13. ff2 = ff1 @ W_sq^T + b_sq
    gemm_lds<64,128,1|8><<<dim3(128, 2), 256, 0, stream>>>(ff1b, wsqb, NT, DM, DI,
                                                           b_sq, nullptr, ff2, nullptr);
    // 14. out = ln(hln + ff2); also writes passthrough out2 = x
    lnorm<<<NT / 4, 256, 0, stream>>>(hln, ff2, ln2_g, ln2_b, outp, nullptr,
                                      x, outp + (size_t)NT * DM);
}

// Round 4
// 286.067 us; speedup vs baseline: 1.0867x; 1.0116x over previous
//
#include <hip/hip_runtime.h>
#include <stdint.h>

#define NT 8192      // sequence length
#define DM 256       // d_model
#define DI 512       // d_inner
#define DS 16        // d_state
#define DR 16        // dt_rank
#define NCH 512      // scan chunks
#define LCH 16       // chunk length (NCH*LCH == NT)
#define NSUP 32      // super-chunks
#define CPS 16       // chunks per super-chunk (NSUP*CPS == NCH)

typedef __bf16 bf16_t;
typedef bf16_t bf16x8 __attribute__((ext_vector_type(8)));
typedef float f32x4 __attribute__((ext_vector_type(4)));

// ---------- helpers ----------
__device__ __forceinline__ unsigned short f2b(float f) {
    union { float f; unsigned int i; } v; v.f = f;
    unsigned int r = v.i + 0x7fffu + ((v.i >> 16) & 1u);   // RNE
    return (unsigned short)(r >> 16);
}
__device__ __forceinline__ float b2f(unsigned short u) {
    union { unsigned int i; float f; } v; v.i = ((unsigned int)u) << 16; return v.f;
}
__device__ __forceinline__ bf16x8 ld_frag_lds(const unsigned short* p) {
    union { uint4 u; bf16x8 b; } v;
    v.u = *(const uint4*)p;
    return v.b;
}
// async global->LDS, 16B per lane. LDS side must be base + lane*16 contiguous.
__device__ __forceinline__ void async16(const unsigned short* g, unsigned short* l) {
    __builtin_amdgcn_global_load_lds(
        (const __attribute__((address_space(1))) unsigned int*)g,
        (__attribute__((address_space(3))) unsigned int*)l, 16, 0, 0);
}
__device__ __forceinline__ float fast_softplus(float x) {
    return x > 20.f ? x : __logf(1.f + __expf(x));
}
__device__ __forceinline__ float silu(float x) {
    return x / (1.f + __expf(-x));
}

// ---------- fp32 -> bf16 conversion; W_out (slot 3) is stored TRANSPOSED ------
struct CvtArgs {
    const float* src[7];
    unsigned short* dst[7];
    int cnt[7];
    int total;
};
__global__ __launch_bounds__(256) void cvt_all(CvtArgs a) {
    int i = blockIdx.x * 256 + threadIdx.x;
    if (i >= a.total) return;
    #pragma unroll
    for (int s = 0; s < 7; s++) {
        if (i < a.cnt[s]) {
            unsigned short v = f2b(a.src[s][i]);
            if (s == 3) {                     // W_out [256][512] -> woutT [512][256]
                int k = i >> 9, j = i & 511;
                a.dst[s][j * 256 + k] = v;
            } else {
                a.dst[s][i] = v;
            }
            return;
        }
        i -= a.cnt[s];
    }
}

// ---------- m97-style MFMA GEMM: C[M,N] = A[M,K] @ B[N,K]^T (+epilogue) ----------
// FLAGS: 1=bias  2=relu  4=residual(+resid[m*N+n])  8=store f32  16=store bf16
template<int BM, int BN, int FLAGS>
__global__ __launch_bounds__(256) void gemm_lds(
    const unsigned short* __restrict__ A, const unsigned short* __restrict__ B,
    int M, int N, int K,
    const float* __restrict__ bias, const float* __restrict__ resid,
    float* __restrict__ Cf, unsigned short* __restrict__ Cb)
{
    constexpr int MI = BM / 32;
    constexpr int NJ = BN / 32;
    __shared__ unsigned short sA[BM * 64];   // row-major, NO pad (global_load_lds)
    __shared__ unsigned short sB[BN * 64];
    const int tid = threadIdx.x;
    const int m0 = blockIdx.x * BM;
    const int n0 = blockIdx.y * BN;
    const int wave = tid >> 6, lane = tid & 63;
    const int wm = (wave & 1) * (BM / 2);
    const int wn = (wave >> 1) * (BN / 2);
    const int qm = lane >> 4, rm = lane & 15;

    f32x4 acc[MI][NJ];
    #pragma unroll
    for (int i = 0; i < MI; i++)
        #pragma unroll
        for (int j = 0; j < NJ; j++)
            #pragma unroll
            for (int r = 0; r < 4; r++) acc[i][j][r] = 0.f;

    const int sr = tid >> 3;
    const int sc = (tid & 7) * 8;

    for (int k0 = 0; k0 < K; k0 += 64) {
        __syncthreads();
        #pragma unroll
        for (int j = 0; j < BM / 32; j++) {
            int r = sr + j * 32;
            async16(A + (size_t)(m0 + r) * K + k0 + sc, &sA[r * 64 + sc]);
        }
        #pragma unroll
        for (int j = 0; j < BN / 32; j++) {
            int r = sr + j * 32;
            if (n0 + r < N)
                async16(B + (size_t)(n0 + r) * K + k0 + sc, &sB[r * 64 + sc]);
        }
        __syncthreads();
        #pragma unroll
        for (int ks = 0; ks < 64; ks += 32) {
            bf16x8 af[MI], bfr[NJ];
            #pragma unroll
            for (int i = 0; i < MI; i++)
                af[i] = ld_frag_lds(&sA[(wm + i * 16 + rm) * 64 + ks + qm * 8]);
            #pragma unroll
            for (int j = 0; j < NJ; j++)
                bfr[j] = ld_frag_lds(&sB[(wn + j * 16 + rm) * 64 + ks + qm * 8]);
            #pragma unroll
            for (int i = 0; i < MI; i++)
                #pragma unroll
                for (int j = 0; j < NJ; j++)
                    acc[i][j] = __builtin_amdgcn_mfma_f32_16x16x32_bf16(
                        af[i], bfr[j], acc[i][j], 0, 0, 0);
        }
    }

    // epilogue: D[m][n]: n = lane&15, m = (lane>>4)*4 + reg   [m89-verified]
    #pragma unroll
    for (int i = 0; i < MI; i++) {
        int mrow = m0 + wm + i * 16 + qm * 4;
        #pragma unroll
        for (int j = 0; j < NJ; j++) {
            int ncol = n0 + wn + j * 16 + rm;
            if (ncol < N) {
                #pragma unroll
                for (int r = 0; r < 4; r++) {
                    float v = acc[i][j][r];
                    int mm = mrow + r;
                    if constexpr (FLAGS & 1) v += bias[ncol];
                    if constexpr (FLAGS & 4) v += resid[(size_t)mm * N + ncol];
                    if constexpr (FLAGS & 2) v = v > 0.f ? v : 0.f;
                    if constexpr (FLAGS & 8) Cf[(size_t)mm * N + ncol] = v;
                    if constexpr (FLAGS & 16) Cb[(size_t)mm * N + ncol] = f2b(v);
                }
            }
        }
    }
}

// ---------- depthwise causal conv (k=4) + SiLU -> bf16 (for W_x gemm) ----------
__global__ __launch_bounds__(256) void conv_silu_b(
    const unsigned short* __restrict__ xz, const float* __restrict__ cw,
    const float* __restrict__ cb, unsigned short* __restrict__ xcb)
{
    int idx = blockIdx.x * 256 + threadIdx.x;   // t*DI + d
    int d = idx & (DI - 1), t = idx >> 9;
    float v = cb[d];
    #pragma unroll
    for (int k = 0; k < 4; k++) {
        int tt = t - 3 + k;
        if (tt >= 0) v += b2f(xz[(size_t)tt * 1024 + d]) * cw[d * 4 + k];
    }
    xcb[idx] = f2b(silu(v));
}

// ---------- scan phase 1: conv+dt fused; per-chunk decay product + local end ----
__global__ __launch_bounds__(256, 4) void scan1(
    const unsigned short* __restrict__ xz, const float* __restrict__ cw,
    const float* __restrict__ cbp, const float* __restrict__ dbl,
    const float* __restrict__ Wdt, const float* __restrict__ bdt,
    const float* __restrict__ A_log,
    float* __restrict__ Ac, float* __restrict__ Bc)
{
    __shared__ float sR[LCH * 48];   // chunk's dbl rows (contiguous copy)
    const int d = blockIdx.x * 256 + threadIdx.x;  // 0..511
    const int c = blockIdx.y;
    const int t0 = c * LCH;
    {   // LCH*48 = 768 floats = 192 float4, contiguous in dbl
        const float4* src = (const float4*)(dbl + (size_t)t0 * 48);
        if (threadIdx.x < 192) ((float4*)sR)[threadIdx.x] = src[threadIdx.x];
    }
    __syncthreads();
    const float cw0 = cw[d*4], cw1 = cw[d*4+1], cw2 = cw[d*4+2], cw3 = cw[d*4+3];
    const float cb = cbp[d];
    const unsigned short* xzp = xz + d;
    float x0 = (t0 >= 3) ? b2f(xzp[(size_t)(t0-3) * 1024]) : 0.f;
    float x1 = (t0 >= 2) ? b2f(xzp[(size_t)(t0-2) * 1024]) : 0.f;
    float x2 = (t0 >= 1) ? b2f(xzp[(size_t)(t0-1) * 1024]) : 0.f;
    float w[DR], A[DS], h[DS];
    #pragma unroll
    for (int j = 0; j < DR; j++) w[j] = Wdt[d * DR + j];
    const float bd = bdt[d];
    #pragma unroll
    for (int s = 0; s < DS; s++) { A[s] = -__expf(A_log[d * DS + s]); h[s] = 0.f; }
    float sumdt = 0.f;
    #pragma unroll 4
    for (int t = 0; t < LCH; t++) {
        float x3 = b2f(xzp[(size_t)(t0 + t) * 1024]);
        float cv = cb + x0 * cw0 + x1 * cw1 + x2 * cw2 + x3 * cw3;
        x0 = x1; x1 = x2; x2 = x3;
        float xcv = silu(cv);
        const float* r = &sR[t * 48];
        float4 rd[4], rb[4];
        #pragma unroll
        for (int k = 0; k < 4; k++) { rd[k] = ((const float4*)r)[k]; rb[k] = ((const float4*)r)[4 + k]; }
        float accd = bd;
        #pragma unroll
        for (int k = 0; k < 4; k++)
            accd += rd[k].x * w[4*k] + rd[k].y * w[4*k+1] + rd[k].z * w[4*k+2] + rd[k].w * w[4*k+3];
        float dtv = fast_softplus(accd);
        sumdt += dtv;
        float dtx = dtv * xcv;
        const float* bptr = (const float*)rb;
        #pragma unroll
        for (int s = 0; s < DS; s++)
            h[s] = __expf(dtv * A[s]) * h[s] + dtx * bptr[s];
    }
    #pragma unroll
    for (int s = 0; s < DS; s++) {
        size_t off = ((size_t)c * DS + s) * DI + d;
        Ac[off] = __expf(sumdt * A[s]);
        Bc[off] = h[s];
    }
}

// ---------- scan phase 2a: per-super-chunk local scan ----------
__global__ __launch_bounds__(256) void scan2a(
    const float* __restrict__ Ac, const float* __restrict__ Bc,
    float* __restrict__ Ap, float* __restrict__ Hl,
    float* __restrict__ Es, float* __restrict__ Ds)
{
    int p = blockIdx.x * 256 + threadIdx.x;   // (s*DI+d) 0..8191
    int j = blockIdx.y;                        // super-chunk 0..NSUP-1
    float h = 0.f, P = 1.f;
    for (int cc = 0; cc < CPS; cc++) {
        size_t off = (size_t)(j * CPS + cc) * 8192 + p;
        Hl[off] = h; Ap[off] = P;
        float a = Ac[off];
        h = a * h + Bc[off];
        P *= a;
    }
    Es[(size_t)j * 8192 + p] = h;
    Ds[(size_t)j * 8192 + p] = P;
}

// ---------- scan phase 2b: NSUP-step scan over super-chunks ----------
__global__ __launch_bounds__(256) void scan2b(
    const float* __restrict__ Es, const float* __restrict__ Ds,
    float* __restrict__ Ss)
{
    int p = blockIdx.x * 256 + threadIdx.x;
    float S = 0.f;
    for (int j = 0; j < NSUP; j++) {
        Ss[(size_t)j * 8192 + p] = S;
        S = Ds[(size_t)j * 8192 + p] * S + Es[(size_t)j * 8192 + p];
    }
}

// ---------- scan phase 3: replay (conv+dt recomputed); fuse +Dp*xc, *silu(z) ---
__global__ __launch_bounds__(256, 4) void scan3(
    const unsigned short* __restrict__ xz, const float* __restrict__ cw,
    const float* __restrict__ cbp, const float* __restrict__ dbl,
    const float* __restrict__ Wdt, const float* __restrict__ bdt,
    const float* __restrict__ A_log, const float* __restrict__ Dpp,
    const float* __restrict__ Ap, const float* __restrict__ Hl,
    const float* __restrict__ Ss, unsigned short* __restrict__ ygb)
{
    __shared__ float sR[LCH * 48];
    const int d = blockIdx.x * 256 + threadIdx.x;
    const int c = blockIdx.y;
    const int jsup = c / CPS;
    const int t0 = c * LCH;
    {
        const float4* src = (const float4*)(dbl + (size_t)t0 * 48);
        if (threadIdx.x < 192) ((float4*)sR)[threadIdx.x] = src[threadIdx.x];
    }
    __syncthreads();
    const float cw0 = cw[d*4], cw1 = cw[d*4+1], cw2 = cw[d*4+2], cw3 = cw[d*4+3];
    const float cb = cbp[d];
    const unsigned short* xzp = xz + d;
    const unsigned short* zp  = xz + DI + d;
    float x0 = (t0 >= 3) ? b2f(xzp[(size_t)(t0-3) * 1024]) : 0.f;
    float x1 = (t0 >= 2) ? b2f(xzp[(size_t)(t0-2) * 1024]) : 0.f;
    float x2 = (t0 >= 1) ? b2f(xzp[(size_t)(t0-1) * 1024]) : 0.f;
    float w[DR], A[DS], h[DS];
    #pragma unroll
    for (int j = 0; j < DR; j++) w[j] = Wdt[d * DR + j];
    const float bd = bdt[d];
    const float dpv = Dpp[d];
    #pragma unroll
    for (int s = 0; s < DS; s++) {
        A[s] = -__expf(A_log[d * DS + s]);
        size_t off = (size_t)c * 8192 + s * DI + d;
        h[s] = Ap[off] * Ss[(size_t)jsup * 8192 + s * DI + d] + Hl[off];
    }
    #pragma unroll 4
    for (int t = 0; t < LCH; t++) {
        float x3 = b2f(xzp[(size_t)(t0 + t) * 1024]);
        float zv = b2f(zp[(size_t)(t0 + t) * 1024]);
        float cv = cb + x0 * cw0 + x1 * cw1 + x2 * cw2 + x3 * cw3;
        x0 = x1; x1 = x2; x2 = x3;
        float xcv = silu(cv);
        const float* r = &sR[t * 48];
        float4 rd[4], rb[4], rc[4];
        #pragma unroll
        for (int k = 0; k < 4; k++) {
            rd[k] = ((const float4*)r)[k];
            rb[k] = ((const float4*)r)[4 + k];
            rc[k] = ((const float4*)r)[8 + k];
        }
        float accd = bd;
        #pragma unroll
        for (int k = 0; k < 4; k++)
            accd += rd[k].x * w[4*k] + rd[k].y * w[4*k+1] + rd[k].z * w[4*k+2] + rd[k].w * w[4*k+3];
        float dtv = fast_softplus(accd);
        float dtx = dtv * xcv;
        const float* bptr = (const float*)rb;
        const float* cptr = (const float*)rc;
        float y = 0.f;
        #pragma unroll
        for (int s = 0; s < DS; s++) {
            h[s] = __expf(dtv * A[s]) * h[s] + dtx * bptr[s];
            y += h[s] * cptr[s];
        }
        ygb[(size_t)(t0 + t) * DI + d] = f2b((y + dpv * xcv) * silu(zv));
    }
}

// ---------- LayerNorm over 256 cols (one wave per row) ----------
// optional add X2; optional passthrough copy (csrc->cdst, same row layout)
__global__ __launch_bounds__(256) void lnorm(
    const float* __restrict__ X, const float* __restrict__ X2,
    const float* __restrict__ g, const float* __restrict__ b,
    float* __restrict__ outf, unsigned short* __restrict__ outb,
    const float* __restrict__ csrc, float* __restrict__ cdst)
{
    int wave = threadIdx.x >> 6, lane = threadIdx.x & 63;
    int row = blockIdx.x * 4 + wave;
    const float* x = X + (size_t)row * DM;
    float v[4];
    #pragma unroll
    for (int i = 0; i < 4; i++) {
        int col = lane + i * 64;
        v[i] = x[col];
        if (X2) v[i] += X2[(size_t)row * DM + col];
    }
    if (cdst) {
        #pragma unroll
        for (int i = 0; i < 4; i++) {
            int col = lane + i * 64;
            cdst[(size_t)row * DM + col] = csrc[(size_t)row * DM + col];
        }
    }
    float s = v[0] + v[1] + v[2] + v[3];
    float s2 = v[0]*v[0] + v[1]*v[1] + v[2]*v[2] + v[3]*v[3];
    #pragma unroll
    for (int m = 1; m < 64; m <<= 1) {
        s  += __shfl_xor(s, m, 64);
        s2 += __shfl_xor(s2, m, 64);
    }
    float mean = s * (1.f / DM);
    float var = s2 * (1.f / DM) - mean * mean;
    float inv = rsqrtf(var + 1e-5f);
    #pragma unroll
    for (int i = 0; i < 4; i++) {
        int col = lane + i * 64;
        float o = (v[i] - mean) * inv * g[col] + b[col];
        if (outf) outf[(size_t)row * DM + col] = o;
        if (outb) outb[(size_t)row * DM + col] = f2b(o);
    }
}

// ---------- workspace layout (bytes; ws_size = 256 MiB) ----------
static constexpr size_t OFF_XZB   = 0;            // bf16 [8192][1024]  16777216
static constexpr size_t OFF_XCB   = 16777216;     // bf16 [8192][512]    8388608
static constexpr size_t OFF_DBL   = 25165824;     // f32 [8192][48]      1572864
static constexpr size_t OFF_AC    = 26738688;     // f32 [512][16][512] 16777216
static constexpr size_t OFF_BC    = 43515904;     // f32                16777216
static constexpr size_t OFF_HL    = 60293120;     // f32 [512][8192]    16777216
static constexpr size_t OFF_AP    = 77070336;     // f32 [512][8192]    16777216
static constexpr size_t OFF_ES    = 93847552;     // f32 [32][8192]      1048576
static constexpr size_t OFF_DS2   = 94896128;     // f32 [32][8192]      1048576
static constexpr size_t OFF_SS    = 95944704;     // f32 [32][8192]      1048576
static constexpr size_t OFF_YGB   = 96993280;     // bf16 [8192][512]    8388608
static constexpr size_t OFF_XB    = 105381888;    // bf16 [8192][256]    4194304
static constexpr size_t OFF_WINB  = 109576192;    // bf16 [1024][256]     524288
static constexpr size_t OFF_WXB   = 110100480;    // bf16 [48][512]        49152
static constexpr size_t OFF_WOUTT = 110149632;    // bf16 [512][256]      262144 (W_out^T)
static constexpr size_t OFF_WLINB = 110411776;    // bf16 [256][256]      131072
static constexpr size_t OFF_WEXPB = 110542848;    // bf16 [512][256]      262144
static constexpr size_t OFF_WSQB  = 110804992;    // bf16 [256][512]      262144
static constexpr size_t OFF_WCOMB = 111067136;    // bf16 [256][512]      262144 (W_lin@W_out)
// aliases (producer runs strictly after the aliased array's last reader)
static constexpr size_t OFF_H2    = OFF_AC;                // f32  [8192][256] (Ac dead after scan2a)
static constexpr size_t OFF_HLN   = OFF_BC;                // f32  [8192][256] (Bc dead after scan2a)
static constexpr size_t OFF_HLNB  = OFF_BC + 8388608;      // bf16 [8192][256]
static constexpr size_t OFF_FF1B  = OFF_HL;                // bf16 [8192][512] (Hl dead after scan3)
static constexpr size_t OFF_FF2   = OFF_AP;                // f32  [8192][256] (Ap dead after scan3)

extern "C" void kernel_launch(void* const* d_in, const int* in_sizes, int n_in,
                              void* d_out, int out_size, void* d_ws, size_t ws_size,
                              hipStream_t stream)
{
    const float* x      = (const float*)d_in[0];
    const float* W_in   = (const float*)d_in[2];
    const float* conv_w = (const float*)d_in[3];
    const float* conv_b = (const float*)d_in[4];
    const float* W_x    = (const float*)d_in[5];
    const float* W_dt   = (const float*)d_in[6];
    const float* b_dt   = (const float*)d_in[7];
    const float* A_log  = (const float*)d_in[8];
    const float* Dp     = (const float*)d_in[9];
    const float* W_out  = (const float*)d_in[10];
    const float* W_lin  = (const float*)d_in[11];
    const float* b_lin  = (const float*)d_in[12];
    const float* ln1_g  = (const float*)d_in[13];
    const float* ln1_b  = (const float*)d_in[14];
    const float* W_exp  = (const float*)d_in[15];
    const float* b_exp  = (const float*)d_in[16];
    const float* W_sq   = (const float*)d_in[17];
    const float* b_sq   = (const float*)d_in[18];
    const float* ln2_g  = (const float*)d_in[19];
    const float* ln2_b  = (const float*)d_in[20];

    char* ws = (char*)d_ws;
    unsigned short* xzb = (unsigned short*)(ws + OFF_XZB);
    unsigned short* xcb = (unsigned short*)(ws + OFF_XCB);
    float* dbl  = (float*)(ws + OFF_DBL);
    float* Ac   = (float*)(ws + OFF_AC);
    float* Bc   = (float*)(ws + OFF_BC);
    float* Hl   = (float*)(ws + OFF_HL);
    float* Ap   = (float*)(ws + OFF_AP);
    float* Es   = (float*)(ws + OFF_ES);
    float* Ds   = (float*)(ws + OFF_DS2);
    float* Ss   = (float*)(ws + OFF_SS);
    unsigned short* ygb   = (unsigned short*)(ws + OFF_YGB);
    unsigned short* xb    = (unsigned short*)(ws + OFF_XB);
    unsigned short* winb  = (unsigned short*)(ws + OFF_WINB);
    unsigned short* wxb   = (unsigned short*)(ws + OFF_WXB);
    unsigned short* woutT = (unsigned short*)(ws + OFF_WOUTT);
    unsigned short* wlinb = (unsigned short*)(ws + OFF_WLINB);
    unsigned short* wexpb = (unsigned short*)(ws + OFF_WEXPB);
    unsigned short* wsqb  = (unsigned short*)(ws + OFF_WSQB);
    unsigned short* wcomb = (unsigned short*)(ws + OFF_WCOMB);
    float* h2   = (float*)(ws + OFF_H2);
    float* hln  = (float*)(ws + OFF_HLN);
    unsigned short* hlnb  = (unsigned short*)(ws + OFF_HLNB);
    unsigned short* ff1b  = (unsigned short*)(ws + OFF_FF1B);
    float* ff2  = (float*)(ws + OFF_FF2);
    float* outp = (float*)d_out;

    // 1. bf16 conversions (W_out transposed)
    CvtArgs ca;
    ca.src[0] = x;     ca.dst[0] = xb;    ca.cnt[0] = NT * DM;
    ca.src[1] = W_in;  ca.dst[1] = winb;  ca.cnt[1] = 1024 * DM;
    ca.src[2] = W_x;   ca.dst[2] = wxb;   ca.cnt[2] = 48 * DI;
    ca.src[3] = W_out; ca.dst[3] = woutT; ca.cnt[3] = DM * DI;
    ca.src[4] = W_lin; ca.dst[4] = wlinb; ca.cnt[4] = DM * DM;
    ca.src[5] = W_exp; ca.dst[5] = wexpb; ca.cnt[5] = DI * DM;
    ca.src[6] = W_sq;  ca.dst[6] = wsqb;  ca.cnt[6] = DM * DI;
    ca.total = ca.cnt[0]+ca.cnt[1]+ca.cnt[2]+ca.cnt[3]+ca.cnt[4]+ca.cnt[5]+ca.cnt[6];
    cvt_all<<<(ca.total + 255) / 256, 256, 0, stream>>>(ca);

    // 2. Wcomb = W_lin @ W_out  [256,512] bf16  (A=W_lin[256,256], B=W_out^T[512,256])
    gemm_lds<64,64,16><<<dim3(4, 8), 256, 0, stream>>>(wlinb, woutT, DM, DI, DM,
                                                       nullptr, nullptr, nullptr, wcomb);
    // 3. xz = x @ W_in^T        [8192,1024] bf16
    gemm_lds<128,128,16><<<dim3(64, 8), 256, 0, stream>>>(xb, winb, NT, 1024, DM,
                                                          nullptr, nullptr, nullptr, xzb);
    // 4. conv+silu -> bf16 (only feeds the W_x gemm; scans recompute in f32)
    conv_silu_b<<<NT * DI / 256, 256, 0, stream>>>(xzb, conv_w, conv_b, xcb);
    // 5. dbl = xc @ W_x^T       [8192,48] f32
    gemm_lds<64,64,8><<<dim3(128, 1), 256, 0, stream>>>(xcb, wxb, NT, 48, DI,
                                                        nullptr, nullptr, dbl, nullptr);
    // 6-9. chunked selective scan (conv & dt fused into scan1/scan3)
    scan1<<<dim3(2, NCH), 256, 0, stream>>>(xzb, conv_w, conv_b, dbl, W_dt, b_dt,
                                            A_log, Ac, Bc);
    scan2a<<<dim3(32, NSUP), 256, 0, stream>>>(Ac, Bc, Ap, Hl, Es, Ds);
    scan2b<<<32, 256, 0, stream>>>(Es, Ds, Ss);
    scan3<<<dim3(2, NCH), 256, 0, stream>>>(xzb, conv_w, conv_b, dbl, W_dt, b_dt,
                                            A_log, Dp, Ap, Hl, Ss, ygb);
    // 10. h2 = yg @ Wcomb^T + b_lin + x   [8192,256] f32   (W_out & W_lin fused)
    gemm_lds<64,64,1|4|8><<<dim3(128, 4), 256, 0, stream>>>(ygb, wcomb, NT, DM, DI,
                                                            b_lin, x, h2, nullptr);
    // 11. ln1
    lnorm<<<NT / 4, 256, 0, stream>>>(h2, nullptr, ln1_g, ln1_b, hln, hlnb,
                                      nullptr, nullptr);
    // 12. ff1 = relu(hln @ W_exp^T + b_exp)  bf16
    gemm_lds<64,128,1|2|16><<<dim3(128, 4), 256, 0, stream>>>(hlnb, wexpb, NT, DI, DM,
                                                              b_exp, nullptr, nullptr, ff1b);
    // 13. ff2 = ff1 @ W_sq^T + b_sq
    gemm_lds<64,64,1|8><<<dim3(128, 4), 256, 0, stream>>>(ff1b, wsqb, NT, DM, DI,
                                                          b_sq, nullptr, ff2, nullptr);
    // 14. out = ln(hln + ff2); also writes passthrough out2 = x
    lnorm<<<NT / 4, 256, 0, stream>>>(hln, ff2, ln2_g, ln2_b, outp, nullptr,
                                      x, outp + (size_t)NT * DM);
}

// Round 5
// 279.129 us; speedup vs baseline: 1.1137x; 1.0249x over previous
//
#include <hip/hip_runtime.h>
#include <stdint.h>

#define NT 8192      // sequence length
#define DM 256       // d_model
#define DI 512       // d_inner
#define DS 16        // d_state
#define DR 16        // dt_rank
#define NCH 512      // scan chunks
#define LCH 16       // chunk length (NCH*LCH == NT)
#define NSUP 32      // super-chunks
#define CPS 16       // chunks per super-chunk (NSUP*CPS == NCH)

typedef __bf16 bf16_t;
typedef bf16_t bf16x8 __attribute__((ext_vector_type(8)));
typedef float f32x4 __attribute__((ext_vector_type(4)));

// ---------- helpers ----------
__device__ __forceinline__ unsigned short f2b(float f) {
    union { float f; unsigned int i; } v; v.f = f;
    unsigned int r = v.i + 0x7fffu + ((v.i >> 16) & 1u);   // RNE
    return (unsigned short)(r >> 16);
}
__device__ __forceinline__ float b2f(unsigned short u) {
    union { unsigned int i; float f; } v; v.i = ((unsigned int)u) << 16; return v.f;
}
__device__ __forceinline__ bf16x8 ld_frag_lds(const unsigned short* p) {
    union { uint4 u; bf16x8 b; } v;
    v.u = *(const uint4*)p;
    return v.b;
}
__device__ __forceinline__ void async16(const unsigned short* g, unsigned short* l) {
    __builtin_amdgcn_global_load_lds(
        (const __attribute__((address_space(1))) unsigned int*)g,
        (__attribute__((address_space(3))) unsigned int*)l, 16, 0, 0);
}
__device__ __forceinline__ float fast_softplus(float x) {
    return x > 20.f ? x : __logf(1.f + __expf(x));
}
__device__ __forceinline__ float silu(float x) {
    return x / (1.f + __expf(-x));
}

// ---------- prep: bf16 cvt (W_out transposed) + Wxdt = W_dt@W_x[:16] + Wbig ----
struct PrepArgs {
    const float* src[6];
    unsigned short* dst[6];
    int cnt[6];
    int cvt_blocks;          // 11008
    const float* W_dt;       // [512][16]
    const float* W_x;        // [48][512]
    unsigned short* wbig;    // [544][512] bf16: rows 0..511 = Wxdt, 512..543 = W_x[16:48]
};
__global__ __launch_bounds__(256) void prep(PrepArgs a) {
    int blk = blockIdx.x;
    if (blk < a.cvt_blocks) {
        int i = blk * 256 + threadIdx.x;
        #pragma unroll
        for (int s = 0; s < 6; s++) {
            if (i < a.cnt[s]) {
                unsigned short v = f2b(a.src[s][i]);
                if (s == 2) {                 // W_out [256][512] -> woutT [512][256]
                    int k = i >> 9, j = i & 511;
                    a.dst[s][j * 256 + k] = v;
                } else {
                    a.dst[s][i] = v;
                }
                return;
            }
            i -= a.cnt[s];
        }
    } else if (blk < a.cvt_blocks + 1024) {   // Wxdt rows
        int i = (blk - a.cvt_blocks) * 256 + threadIdx.x;
        int d = i >> 9, k = i & 511;
        float acc = 0.f;
        #pragma unroll
        for (int j = 0; j < 16; j++) acc += a.W_dt[d * 16 + j] * a.W_x[j * 512 + k];
        a.wbig[d * 512 + k] = f2b(acc);
    } else {                                  // W_x rows 16..47 -> wbig rows 512..543
        int i = (blk - a.cvt_blocks - 1024) * 256 + threadIdx.x;
        int j = i >> 9, k = i & 511;
        a.wbig[(512 + j) * 512 + k] = f2b(a.W_x[(16 + j) * 512 + k]);
    }
}

// ---------- m97-style MFMA GEMM: C[M,N] = A[M,K] @ B[N,K]^T (+epilogue) ----------
// FLAGS: 1=bias 2=relu 4=residual 8=store f32 16=store bf16
//        32=proj epilogue: col<512 -> softplus(v+bias)->Cf (stride 512);
//                          col in [512,544) -> Cf2 (stride 32)
template<int BM, int BN, int FLAGS>
__global__ __launch_bounds__(256) void gemm_lds(
    const unsigned short* __restrict__ A, const unsigned short* __restrict__ B,
    int M, int N, int K,
    const float* __restrict__ bias, const float* __restrict__ resid,
    float* __restrict__ Cf, unsigned short* __restrict__ Cb,
    float* __restrict__ Cf2)
{
    constexpr int MI = BM / 32;
    constexpr int NJ = BN / 32;
    __shared__ unsigned short sA[BM * 64];
    __shared__ unsigned short sB[BN * 64];
    const int tid = threadIdx.x;
    const int m0 = blockIdx.x * BM;
    const int n0 = blockIdx.y * BN;
    const int wave = tid >> 6, lane = tid & 63;
    const int wm = (wave & 1) * (BM / 2);
    const int wn = (wave >> 1) * (BN / 2);
    const int qm = lane >> 4, rm = lane & 15;

    f32x4 acc[MI][NJ];
    #pragma unroll
    for (int i = 0; i < MI; i++)
        #pragma unroll
        for (int j = 0; j < NJ; j++)
            #pragma unroll
            for (int r = 0; r < 4; r++) acc[i][j][r] = 0.f;

    const int sr = tid >> 3;
    const int sc = (tid & 7) * 8;

    for (int k0 = 0; k0 < K; k0 += 64) {
        __syncthreads();
        #pragma unroll
        for (int j = 0; j < BM / 32; j++) {
            int r = sr + j * 32;
            async16(A + (size_t)(m0 + r) * K + k0 + sc, &sA[r * 64 + sc]);
        }
        #pragma unroll
        for (int j = 0; j < BN / 32; j++) {
            int r = sr + j * 32;
            if (n0 + r < N)
                async16(B + (size_t)(n0 + r) * K + k0 + sc, &sB[r * 64 + sc]);
        }
        __syncthreads();
        #pragma unroll
        for (int ks = 0; ks < 64; ks += 32) {
            bf16x8 af[MI], bfr[NJ];
            #pragma unroll
            for (int i = 0; i < MI; i++)
                af[i] = ld_frag_lds(&sA[(wm + i * 16 + rm) * 64 + ks + qm * 8]);
            #pragma unroll
            for (int j = 0; j < NJ; j++)
                bfr[j] = ld_frag_lds(&sB[(wn + j * 16 + rm) * 64 + ks + qm * 8]);
            #pragma unroll
            for (int i = 0; i < MI; i++)
                #pragma unroll
                for (int j = 0; j < NJ; j++)
                    acc[i][j] = __builtin_amdgcn_mfma_f32_16x16x32_bf16(
                        af[i], bfr[j], acc[i][j], 0, 0, 0);
        }
    }

    // epilogue: D[m][n]: n = lane&15, m = (lane>>4)*4 + reg   [m89-verified]
    #pragma unroll
    for (int i = 0; i < MI; i++) {
        int mrow = m0 + wm + i * 16 + qm * 4;
        #pragma unroll
        for (int j = 0; j < NJ; j++) {
            int ncol = n0 + wn + j * 16 + rm;
            if (ncol < N) {
                #pragma unroll
                for (int r = 0; r < 4; r++) {
                    float v = acc[i][j][r];
                    int mm = mrow + r;
                    if constexpr (FLAGS & 32) {
                        if (ncol < 512) {
                            v = fast_softplus(v + bias[ncol]);
                            Cf[(size_t)mm * 512 + ncol] = v;
                        } else {
                            Cf2[(size_t)mm * 32 + (ncol - 512)] = v;
                        }
                    } else {
                        if constexpr (FLAGS & 1) v += bias[ncol];
                        if constexpr (FLAGS & 4) v += resid[(size_t)mm * N + ncol];
                        if constexpr (FLAGS & 2) v = v > 0.f ? v : 0.f;
                        if constexpr (FLAGS & 8) Cf[(size_t)mm * N + ncol] = v;
                        if constexpr (FLAGS & 16) Cb[(size_t)mm * N + ncol] = f2b(v);
                    }
                }
            }
        }
    }
}

// ---------- depthwise causal conv (k=4) + SiLU -> bf16 ----------
__global__ __launch_bounds__(256) void conv_silu_b(
    const unsigned short* __restrict__ xz, const float* __restrict__ cw,
    const float* __restrict__ cb, unsigned short* __restrict__ xcb)
{
    int idx = blockIdx.x * 256 + threadIdx.x;   // t*DI + d
    int d = idx & (DI - 1), t = idx >> 9;
    float v = cb[d];
    #pragma unroll
    for (int k = 0; k < 4; k++) {
        int tt = t - 3 + k;
        if (tt >= 0) v += b2f(xz[(size_t)tt * 1024 + d]) * cw[d * 4 + k];
    }
    xcb[idx] = f2b(silu(v));
}

// ---------- scan phase 1: per-chunk decay product + local end (2-way s-split) --
__global__ __launch_bounds__(256) void scan1(
    const unsigned short* __restrict__ xcb, const float* __restrict__ dtf,
    const float* __restrict__ dblf, const float* __restrict__ A_log,
    unsigned short* __restrict__ Acb, unsigned short* __restrict__ Bcb)
{
    __shared__ float sBC[LCH * 32];   // 16 rows x [B(16)|C(16)] f32 = 2 KB
    const int tid = threadIdx.x;
    const int d = blockIdx.x * 128 + (tid >> 1);
    const int sd = tid & 1;           // state-half
    const int c = blockIdx.y;
    const int t0 = c * LCH;
    if (tid < 128)
        ((float4*)sBC)[tid] = ((const float4*)(dblf + (size_t)t0 * 32))[tid];
    __syncthreads();
    float A2[8], h[8];
    #pragma unroll
    for (int s = 0; s < 8; s++) {
        A2[s] = -__expf(A_log[d * 16 + sd * 8 + s]) * 1.44269504f;
        h[s] = 0.f;
    }
    float sumdt = 0.f;
    #pragma unroll 4
    for (int t = 0; t < LCH; t++) {
        float dtv = dtf[(size_t)(t0 + t) * DI + d];
        float xcv = b2f(xcb[(size_t)(t0 + t) * DI + d]);
        float dtx = dtv * xcv;
        sumdt += dtv;
        const float4 b0 = *(const float4*)&sBC[t * 32 + sd * 8];
        const float4 b1 = *(const float4*)&sBC[t * 32 + sd * 8 + 4];
        float bb[8] = {b0.x, b0.y, b0.z, b0.w, b1.x, b1.y, b1.z, b1.w};
        #pragma unroll
        for (int s = 0; s < 8; s++)
            h[s] = exp2f(dtv * A2[s]) * h[s] + dtx * bb[s];
    }
    #pragma unroll
    for (int s = 0; s < 8; s++) {
        size_t off = ((size_t)c * DS + sd * 8 + s) * DI + d;
        Acb[off] = f2b(exp2f(sumdt * A2[s]));
        Bcb[off] = f2b(h[s]);
    }
}

// ---------- scan phase 2a: per-super-chunk local scan ----------
__global__ __launch_bounds__(256) void scan2a(
    const unsigned short* __restrict__ Acb, const unsigned short* __restrict__ Bcb,
    unsigned short* __restrict__ Apb, unsigned short* __restrict__ Hlb,
    float* __restrict__ Es, float* __restrict__ Ds)
{
    int p = blockIdx.x * 256 + threadIdx.x;   // (s*DI+d) 0..8191
    int j = blockIdx.y;                        // super-chunk
    float h = 0.f, P = 1.f;
    for (int cc = 0; cc < CPS; cc++) {
        size_t off = (size_t)(j * CPS + cc) * 8192 + p;
        Hlb[off] = f2b(h); Apb[off] = f2b(P);
        h = b2f(Acb[off]) * h + b2f(Bcb[off]);
        P *= b2f(Acb[off]);
    }
    Es[(size_t)j * 8192 + p] = h;
    Ds[(size_t)j * 8192 + p] = P;
}

// ---------- scan phase 2b: NSUP-step scan over super-chunks ----------
__global__ __launch_bounds__(256) void scan2b(
    const float* __restrict__ Es, const float* __restrict__ Ds,
    float* __restrict__ Ss)
{
    int p = blockIdx.x * 256 + threadIdx.x;
    float S = 0.f;
    for (int j = 0; j < NSUP; j++) {
        Ss[(size_t)j * 8192 + p] = S;
        S = Ds[(size_t)j * 8192 + p] * S + Es[(size_t)j * 8192 + p];
    }
}

// ---------- scan phase 3: replay from composed init (2-way s-split) ----------
__global__ __launch_bounds__(256) void scan3(
    const unsigned short* __restrict__ xcb, const float* __restrict__ dtf,
    const float* __restrict__ dblf, const unsigned short* __restrict__ xzb,
    const float* __restrict__ A_log, const float* __restrict__ Dpp,
    const unsigned short* __restrict__ Apb, const unsigned short* __restrict__ Hlb,
    const float* __restrict__ Ss, unsigned short* __restrict__ ygb)
{
    __shared__ float sBC[LCH * 32];
    const int tid = threadIdx.x;
    const int d = blockIdx.x * 128 + (tid >> 1);
    const int sd = tid & 1;
    const int c = blockIdx.y;
    const int jsup = c / CPS;
    const int t0 = c * LCH;
    if (tid < 128)
        ((float4*)sBC)[tid] = ((const float4*)(dblf + (size_t)t0 * 32))[tid];
    __syncthreads();
    float A2[8], h[8];
    #pragma unroll
    for (int s = 0; s < 8; s++) {
        A2[s] = -__expf(A_log[d * 16 + sd * 8 + s]) * 1.44269504f;
        size_t off = (size_t)c * 8192 + (sd * 8 + s) * DI + d;
        h[s] = b2f(Apb[off]) * Ss[(size_t)jsup * 8192 + (sd * 8 + s) * DI + d]
             + b2f(Hlb[off]);
    }
    const float dpv = Dpp[d];
    #pragma unroll 4
    for (int t = 0; t < LCH; t++) {
        float dtv = dtf[(size_t)(t0 + t) * DI + d];
        float xcv = b2f(xcb[(size_t)(t0 + t) * DI + d]);
        float zv  = b2f(xzb[(size_t)(t0 + t) * 1024 + DI + d]);
        float dtx = dtv * xcv;
        const float4 b0 = *(const float4*)&sBC[t * 32 + sd * 8];
        const float4 b1 = *(const float4*)&sBC[t * 32 + sd * 8 + 4];
        const float4 c0 = *(const float4*)&sBC[t * 32 + 16 + sd * 8];
        const float4 c1 = *(const float4*)&sBC[t * 32 + 16 + sd * 8 + 4];
        float bb[8] = {b0.x, b0.y, b0.z, b0.w, b1.x, b1.y, b1.z, b1.w};
        float cc[8] = {c0.x, c0.y, c0.z, c0.w, c1.x, c1.y, c1.z, c1.w};
        float y = 0.f;
        #pragma unroll
        for (int s = 0; s < 8; s++) {
            h[s] = exp2f(dtv * A2[s]) * h[s] + dtx * bb[s];
            y += h[s] * cc[s];
        }
        y += __shfl_xor(y, 1, 64);
        if (!sd)
            ygb[(size_t)(t0 + t) * DI + d] = f2b((y + dpv * xcv) * silu(zv));
    }
}

// ---------- LayerNorm over 256 cols (one wave per row) ----------
__global__ __launch_bounds__(256) void lnorm(
    const float* __restrict__ X, const float* __restrict__ X2,
    const float* __restrict__ g, const float* __restrict__ b,
    float* __restrict__ outf, unsigned short* __restrict__ outb,
    const float* __restrict__ csrc, float* __restrict__ cdst)
{
    int wave = threadIdx.x >> 6, lane = threadIdx.x & 63;
    int row = blockIdx.x * 4 + wave;
    const float* x = X + (size_t)row * DM;
    float v[4];
    #pragma unroll
    for (int i = 0; i < 4; i++) {
        int col = lane + i * 64;
        v[i] = x[col];
        if (X2) v[i] += X2[(size_t)row * DM + col];
    }
    if (cdst) {
        #pragma unroll
        for (int i = 0; i < 4; i++) {
            int col = lane + i * 64;
            cdst[(size_t)row * DM + col] = csrc[(size_t)row * DM + col];
        }
    }
    float s = v[0] + v[1] + v[2] + v[3];
    float s2 = v[0]*v[0] + v[1]*v[1] + v[2]*v[2] + v[3]*v[3];
    #pragma unroll
    for (int m = 1; m < 64; m <<= 1) {
        s  += __shfl_xor(s, m, 64);
        s2 += __shfl_xor(s2, m, 64);
    }
    float mean = s * (1.f / DM);
    float var = s2 * (1.f / DM) - mean * mean;
    float inv = rsqrtf(var + 1e-5f);
    #pragma unroll
    for (int i = 0; i < 4; i++) {
        int col = lane + i * 64;
        float o = (v[i] - mean) * inv * g[col] + b[col];
        if (outf) outf[(size_t)row * DM + col] = o;
        if (outb) outb[(size_t)row * DM + col] = f2b(o);
    }
}

// ---------- workspace layout (bytes; no aliasing, ~132 MB of 256) ----------
static constexpr size_t OFF_XZB   = 0;          // bf16 [8192][1024]
static constexpr size_t OFF_XCB   = 16777216;   // bf16 [8192][512]
static constexpr size_t OFF_DTF   = 25165824;   // f32  [8192][512]
static constexpr size_t OFF_DBLF  = 41943040;   // f32  [8192][32]
static constexpr size_t OFF_ACB   = 42991616;   // bf16 [512][16][512]
static constexpr size_t OFF_BCB   = 51380224;   // bf16
static constexpr size_t OFF_APB   = 59768832;   // bf16 [512][8192]
static constexpr size_t OFF_HLB   = 68157440;   // bf16
static constexpr size_t OFF_ES    = 76546048;   // f32 [32][8192]
static constexpr size_t OFF_DS2   = 77594624;   // f32
static constexpr size_t OFF_SS    = 78643200;   // f32
static constexpr size_t OFF_YGB   = 79691776;   // bf16 [8192][512]
static constexpr size_t OFF_XB    = 88080384;   // bf16 [8192][256]
static constexpr size_t OFF_WINB  = 92274688;   // bf16 [1024][256]
static constexpr size_t OFF_WOUTT = 92798976;   // bf16 [512][256]
static constexpr size_t OFF_WLINB = 93061120;   // bf16 [256][256]
static constexpr size_t OFF_WEXPB = 93192192;   // bf16 [512][256]
static constexpr size_t OFF_WSQB  = 93454336;   // bf16 [256][512]
static constexpr size_t OFF_WCOMB = 93716480;   // bf16 [256][512]
static constexpr size_t OFF_WBIG  = 93978624;   // bf16 [544][512]
static constexpr size_t OFF_H2    = 94535680;   // f32 [8192][256]
static constexpr size_t OFF_HLN   = 102924288;  // f32 [8192][256]
static constexpr size_t OFF_HLNB  = 111312896;  // bf16 [8192][256]
static constexpr size_t OFF_FF1B  = 115507200;  // bf16 [8192][512]
static constexpr size_t OFF_FF2   = 123895808;  // f32 [8192][256]

extern "C" void kernel_launch(void* const* d_in, const int* in_sizes, int n_in,
                              void* d_out, int out_size, void* d_ws, size_t ws_size,
                              hipStream_t stream)
{
    const float* x      = (const float*)d_in[0];
    const float* W_in   = (const float*)d_in[2];
    const float* conv_w = (const float*)d_in[3];
    const float* conv_b = (const float*)d_in[4];
    const float* W_x    = (const float*)d_in[5];
    const float* W_dt   = (const float*)d_in[6];
    const float* b_dt   = (const float*)d_in[7];
    const float* A_log  = (const float*)d_in[8];
    const float* Dp     = (const float*)d_in[9];
    const float* W_out  = (const float*)d_in[10];
    const float* W_lin  = (const float*)d_in[11];
    const float* b_lin  = (const float*)d_in[12];
    const float* ln1_g  = (const float*)d_in[13];
    const float* ln1_b  = (const float*)d_in[14];
    const float* W_exp  = (const float*)d_in[15];
    const float* b_exp  = (const float*)d_in[16];
    const float* W_sq   = (const float*)d_in[17];
    const float* b_sq   = (const float*)d_in[18];
    const float* ln2_g  = (const float*)d_in[19];
    const float* ln2_b  = (const float*)d_in[20];

    char* ws = (char*)d_ws;
    unsigned short* xzb = (unsigned short*)(ws + OFF_XZB);
    unsigned short* xcb = (unsigned short*)(ws + OFF_XCB);
    float* dtf  = (float*)(ws + OFF_DTF);
    float* dblf = (float*)(ws + OFF_DBLF);
    unsigned short* Acb = (unsigned short*)(ws + OFF_ACB);
    unsigned short* Bcb = (unsigned short*)(ws + OFF_BCB);
    unsigned short* Apb = (unsigned short*)(ws + OFF_APB);
    unsigned short* Hlb = (unsigned short*)(ws + OFF_HLB);
    float* Es   = (float*)(ws + OFF_ES);
    float* Ds   = (float*)(ws + OFF_DS2);
    float* Ss   = (float*)(ws + OFF_SS);
    unsigned short* ygb   = (unsigned short*)(ws + OFF_YGB);
    unsigned short* xb    = (unsigned short*)(ws + OFF_XB);
    unsigned short* winb  = (unsigned short*)(ws + OFF_WINB);
    unsigned short* woutT = (unsigned short*)(ws + OFF_WOUTT);
    unsigned short* wlinb = (unsigned short*)(ws + OFF_WLINB);
    unsigned short* wexpb = (unsigned short*)(ws + OFF_WEXPB);
    unsigned short* wsqb  = (unsigned short*)(ws + OFF_WSQB);
    unsigned short* wcomb = (unsigned short*)(ws + OFF_WCOMB);
    unsigned short* wbig  = (unsigned short*)(ws + OFF_WBIG);
    float* h2   = (float*)(ws + OFF_H2);
    float* hln  = (float*)(ws + OFF_HLN);
    unsigned short* hlnb  = (unsigned short*)(ws + OFF_HLNB);
    unsigned short* ff1b  = (unsigned short*)(ws + OFF_FF1B);
    float* ff2  = (float*)(ws + OFF_FF2);
    float* outp = (float*)d_out;

    // 1. prep: bf16 conversions + Wxdt/Wbig build
    PrepArgs pa;
    pa.src[0] = x;     pa.dst[0] = xb;    pa.cnt[0] = NT * DM;      // 2097152
    pa.src[1] = W_in;  pa.dst[1] = winb;  pa.cnt[1] = 1024 * DM;    // 262144
    pa.src[2] = W_out; pa.dst[2] = woutT; pa.cnt[2] = DM * DI;      // 131072 (transposed)
    pa.src[3] = W_lin; pa.dst[3] = wlinb; pa.cnt[3] = DM * DM;      // 65536
    pa.src[4] = W_exp; pa.dst[4] = wexpb; pa.cnt[4] = DI * DM;      // 131072
    pa.src[5] = W_sq;  pa.dst[5] = wsqb;  pa.cnt[5] = DM * DI;      // 131072
    pa.cvt_blocks = (2097152 + 262144 + 131072 + 65536 + 131072 + 131072) / 256; // 11008
    pa.W_dt = W_dt; pa.W_x = W_x; pa.wbig = wbig;
    prep<<<pa.cvt_blocks + 1024 + 64, 256, 0, stream>>>(pa);

    // 2. Wcomb = W_lin @ W_out  [256,512] bf16
    gemm_lds<64,64,16><<<dim3(4, 8), 256, 0, stream>>>(wlinb, woutT, DM, DI, DM,
        nullptr, nullptr, nullptr, wcomb, nullptr);
    // 3. xz = x @ W_in^T        [8192,1024] bf16
    gemm_lds<128,128,16><<<dim3(64, 8), 256, 0, stream>>>(xb, winb, NT, 1024, DM,
        nullptr, nullptr, nullptr, xzb, nullptr);
    // 4. conv+silu -> bf16
    conv_silu_b<<<NT * DI / 256, 256, 0, stream>>>(xzb, conv_w, conv_b, xcb);
    // 5. proj = xc @ Wbig^T : dt(softplus,f32) cols 0..511, B|C cols 512..543
    gemm_lds<64,64,32><<<dim3(128, 9), 256, 0, stream>>>(xcb, wbig, NT, 544, DI,
        b_dt, nullptr, dtf, nullptr, dblf);
    // 6-9. chunked selective scan
    scan1<<<dim3(4, NCH), 256, 0, stream>>>(xcb, dtf, dblf, A_log, Acb, Bcb);
    scan2a<<<dim3(32, NSUP), 256, 0, stream>>>(Acb, Bcb, Apb, Hlb, Es, Ds);
    scan2b<<<32, 256, 0, stream>>>(Es, Ds, Ss);
    scan3<<<dim3(4, NCH), 256, 0, stream>>>(xcb, dtf, dblf, xzb, A_log, Dp,
                                            Apb, Hlb, Ss, ygb);
    // 10. h2 = yg @ Wcomb^T + b_lin + x   [8192,256] f32
    gemm_lds<64,64,1|4|8><<<dim3(128, 4), 256, 0, stream>>>(ygb, wcomb, NT, DM, DI,
        b_lin, x, h2, nullptr, nullptr);
    // 11. ln1
    lnorm<<<NT / 4, 256, 0, stream>>>(h2, nullptr, ln1_g, ln1_b, hln, hlnb,
                                      nullptr, nullptr);
    // 12. ff1 = relu(hln @ W_exp^T + b_exp)  bf16
    gemm_lds<64,128,1|2|16><<<dim3(128, 4), 256, 0, stream>>>(hlnb, wexpb, NT, DI, DM,
        b_exp, nullptr, nullptr, ff1b, nullptr);
    // 13. ff2 = ff1 @ W_sq^T + b_sq
    gemm_lds<64,64,1|8><<<dim3(128, 4), 256, 0, stream>>>(ff1b, wsqb, NT, DM, DI,
        b_sq, nullptr, ff2, nullptr, nullptr);
    // 14. out = ln(hln + ff2); also writes passthrough out2 = x
    lnorm<<<NT / 4, 256, 0, stream>>>(hln, ff2, ln2_g, ln2_b, outp, nullptr,
                                      x, outp + (size_t)NT * DM);
}